// Round 17
// baseline (417.866 us; speedup 1.0000x reference)
//
#include <hip/hip_runtime.h>
#include <hip/hip_bf16.h>
#include <math.h>

#define NB 32
#define NQ 2048
#define NK 512
#define NE 16
#define NH 32
#define NL 20
#define NHID 50
#define NO 41

#define LOG2E 1.4426950408889634f
#define TWO_LOG2E 2.8853900817779268f

// ws layout (floats):
// gi   : [64][512][96] @ 0        (3,145,728)  OVERLAID with att (gru before attn)
// att  : [65536][64]   @ 0        (4,194,304)  normalized P@val (pre-Wv)
// val  : [32][512][64] @ 4194304  (1,048,576)
// ktab : [512][16]     @ 5242880  (8,192)
// w1p  : [50][64]      @ 5251072  (3,200)      W1 @ Wv
// b1p  : [50]          @ 5254272  (64)         b1 + W1 @ bv
// total ~21.0 MB (proven size)

typedef __attribute__((ext_vector_type(2))) float f32x2;

__device__ __forceinline__ float bperm(int lane, float v) {
  return __builtin_bit_cast(
      float, __builtin_amdgcn_ds_bpermute(lane << 2, __builtin_bit_cast(int, v)));
}

// blocks 0-1: k-table. block 2: fold Wv into W1.
__global__ __launch_bounds__(256) void prep_kernel(
    const float* __restrict__ refq, const float* __restrict__ Wk,
    const float* __restrict__ bk,
    const float* __restrict__ Wv, const float* __restrict__ bv,
    const float* __restrict__ W1, const float* __restrict__ b1,
    float* __restrict__ ktab, float* __restrict__ w1p,
    float* __restrict__ b1p) {
  const int tid = threadIdx.x;
  if (blockIdx.x < 2) {
    const int r = blockIdx.x * 256 + tid;
    const float divs[8] = {1.0f, 0.74989421f, 0.56234133f, 0.42169650f,
                           0.31622777f, 0.23713737f, 0.17782794f, 0.13335214f};
    float pos = refq[r];
    float emb[NE];
#pragma unroll
    for (int m = 0; m < 8; ++m) {
      float a = 48.0f * pos * divs[m];
      emb[2 * m] = sinf(a);
      emb[2 * m + 1] = cosf(a);
    }
#pragma unroll
    for (int e = 0; e < NE; ++e) {
      float acc = bk[e];
#pragma unroll
      for (int i = 0; i < NE; ++i) acc += emb[i] * Wk[e * NE + i];
      ktab[r * NE + e] = acc;
    }
  } else {
    for (int e = tid; e < NHID * 64; e += 256) {
      const int o = e >> 6, i = e & 63;
      float acc = 0.f;
#pragma unroll 4
      for (int d = 0; d < 64; ++d) acc += W1[o * 64 + d] * Wv[d * 64 + i];
      w1p[e] = acc;
    }
    if (tid < NHID) {
      float acc = b1[tid];
#pragma unroll 4
      for (int d = 0; d < 64; ++d) acc += W1[tid * 64 + d] * bv[d];
      b1p[tid] = acc;
    }
  }
}

// Input-side gates, fully parallel; pre-scaled for exp2-based activations.
__global__ __launch_bounds__(256) void prep_gi_kernel(
    const float* __restrict__ z,
    const float* __restrict__ Wih_f, const float* __restrict__ bih_f,
    const float* __restrict__ bhh_f,
    const float* __restrict__ Wih_b, const float* __restrict__ bih_b,
    const float* __restrict__ bhh_b, float* __restrict__ gi) {
  const int row = blockIdx.x * 256 + threadIdx.x;  // chain*512 + t
  const int c = row >> 9, t = row & 511;
  const int dir = c >> 5, b = c & 31;
  const float* __restrict__ Wih = dir ? Wih_b : Wih_f;
  const float* __restrict__ bih = dir ? bih_b : bih_f;
  const float* __restrict__ bhh = dir ? bhh_b : bhh_f;
  const float* __restrict__ zr = z + ((size_t)b * NK + t) * NL;
  float x[NL];
#pragma unroll
  for (int i = 0; i < NL; ++i) x[i] = zr[i];
  float* __restrict__ go = gi + (size_t)row * 96;
  for (int g = 0; g < 96; ++g) {
    float acc = bih[g] + (g < 64 ? bhh[g] : 0.f);
#pragma unroll
    for (int i = 0; i < NL; ++i) acc += x[i] * Wih[g * NL + i];
    go[g] = acc * (g < 64 ? LOG2E : TWO_LOG2E);
  }
}

// Serial GRU (round-13, PASSED at 134 us): 2 chains per wave, full 32-dots,
// ONE DS round per step, exp2-folded activations, pk-FMA, pointer-walked IO.
__global__ __launch_bounds__(64) void gru_kernel(
    const float* __restrict__ gi,
    const float* __restrict__ Whh_f, const float* __restrict__ bhh_f,
    const float* __restrict__ Whh_b, const float* __restrict__ bhh_b,
    float* __restrict__ val) {
  __shared__ __align__(16) float hbuf[64];  // [chain-half][32]
  const int l = threadIdx.x;
  const int j = l & 31, half = l >> 5;
  const int c = blockIdx.x * 2 + half;   // 2|32 => both halves same dir
  const int dir = c >> 5, b = c & 31;
  const int hb = half * 32;
  const float* __restrict__ Whh = dir ? Whh_b : Whh_f;
  const float* __restrict__ bhh = dir ? bhh_b : bhh_f;

  // weights pre-scaled: r,z x log2e; n x 2*log2e (gi scaled to match)
  f32x2 wr[16], wz[16], wn[16];
#pragma unroll
  for (int i = 0; i < 16; ++i) {
    wr[i] = f32x2{Whh[j * 32 + 2 * i], Whh[j * 32 + 2 * i + 1]} * LOG2E;
    wz[i] = f32x2{Whh[(j + 32) * 32 + 2 * i], Whh[(j + 32) * 32 + 2 * i + 1]} *
            LOG2E;
    wn[i] = f32x2{Whh[(j + 64) * 32 + 2 * i], Whh[(j + 64) * 32 + 2 * i + 1]} *
            TWO_LOG2E;
  }
  const float bhn = bhh[j + 64] * TWO_LOG2E;
  float h = 0.f;
  hbuf[l] = 0.f;

  const float* __restrict__ gic = gi + (size_t)c * NK * 96;
  const int gstart = dir ? (NK - 1) * 96 : 0;
  const int gstride = dir ? -96 : 96;
  float* __restrict__ vp =
      val + ((size_t)b * NK + (dir ? NK - 1 : 0)) * 64 + dir * 32 + j;
  const int vstride = dir ? -64 : 64;

  float r0, z0, n0, r1, z1, n1, r2, z2, n2, r3, z3, n3;
  int gidx = gstart;
  auto giload = [&](float& gr, float& gz, float& gn) {
    const float* p = gic + gidx;
    gr = p[j];
    gz = p[32 + j];
    gn = p[64 + j];
    gidx += gstride;
  };
  giload(r0, z0, n0);
  giload(r1, z1, n1);
  giload(r2, z2, n2);
  giload(r3, z3, n3);

  auto step = [&](bool pf, float& gr, float& gz, float& gn) {
    const float gir = gr, giz = gz, gin = gn;
    if (pf) giload(gr, gz, gn);  // global prefetch (vmcnt queue)
    hbuf[l] = h;  // same-wave LDS is in-order (proven rounds 4-16)
    f32x2 hv[16];
#pragma unroll
    for (int t = 0; t < 4; ++t) {
      const float4 hq = *(const float4*)&hbuf[hb + t * 8];
      const float4 hq2 = *(const float4*)&hbuf[hb + t * 8 + 4];
      hv[t * 4 + 0] = f32x2{hq.x, hq.y};
      hv[t * 4 + 1] = f32x2{hq.z, hq.w};
      hv[t * 4 + 2] = f32x2{hq2.x, hq2.y};
      hv[t * 4 + 3] = f32x2{hq2.z, hq2.w};
    }
    f32x2 sr2 = {0.f, 0.f}, sz2 = {0.f, 0.f}, sn2 = {0.f, 0.f};
    f32x2 sr3 = {0.f, 0.f}, sz3 = {0.f, 0.f}, sn3 = {0.f, 0.f};
#pragma unroll
    for (int t = 0; t < 8; ++t) {
      sr2 = __builtin_elementwise_fma(wr[t], hv[t], sr2);
      sz2 = __builtin_elementwise_fma(wz[t], hv[t], sz2);
      sn2 = __builtin_elementwise_fma(wn[t], hv[t], sn2);
      sr3 = __builtin_elementwise_fma(wr[8 + t], hv[8 + t], sr3);
      sz3 = __builtin_elementwise_fma(wz[8 + t], hv[8 + t], sz3);
      sn3 = __builtin_elementwise_fma(wn[8 + t], hv[8 + t], sn3);
    }
    const float sr = (sr2.x + sr2.y) + (sr3.x + sr3.y);
    const float sz = (sz2.x + sz2.y) + (sz3.x + sz3.y);
    const float sn = (sn2.x + sn2.y) + (sn3.x + sn3.y);
    const float rg =
        __builtin_amdgcn_rcpf(1.0f + __builtin_amdgcn_exp2f(-(gir + sr)));
    const float ug =
        __builtin_amdgcn_rcpf(1.0f + __builtin_amdgcn_exp2f(-(giz + sz)));
    const float ng =
        1.0f - 2.0f * __builtin_amdgcn_rcpf(
                          __builtin_amdgcn_exp2f(gin + rg * (sn + bhn)) + 1.0f);
    h = ng + ug * (h - ng);
    *vp = h;
    vp += vstride;
  };
  for (int s = 0; s < NK; s += 4) {
    step(s + 4 < NK, r0, z0, n0);
    step(s + 5 < NK, r1, z1, n1);
    step(s + 6 < NK, r2, z2, n2);
    step(s + 7 < NK, r3, z3, n3);
  }
}

// R=8 attention v6: 8 waves/block, wave w owns 64-key block khi=w, processed
// as 8 SUB-PHASES of 8 keys: (1) 8 scores+exp into regs, (2) 8 ds_writes to
// plds[wave][8][64] (lane-consecutive: g*8+r8==lane), (3) PV pass reading
// pm[8] as 2 broadcast b128 per key. ONE DS round per 8 keys (was per key).
__global__ __launch_bounds__(512) void attn_core_kernel(
    const float* __restrict__ tsteps, const float* __restrict__ ktab,
    const float* __restrict__ val,
    const float* __restrict__ Wq, const float* __restrict__ bq,
    float* __restrict__ att) {
  __shared__ __align__(16) float cbuf[8][64][8];     // 16 KB combine buffer
  __shared__ __align__(16) float plds[8][8][64];     // 16 KB p staging
  __shared__ float lbuf[8][64];                      // 2 KB lsum partials
  __shared__ float wqs[NE * NE];
  __shared__ float bqs[NE];
  const int tid = threadIdx.x;
  for (int i = tid; i < NE * NE; i += 512) wqs[i] = Wq[i];
  if (tid < NE) bqs[tid] = bq[tid];
  __syncthreads();

  const int lane = tid & 63;
  const int g = lane >> 3;      // group 0..7
  const int r8 = lane & 7;      // row-in-group for scoring; d-eighth for acc
  const int wave = tid >> 6;    // k-eighth owner (khi = wave)
  const int rowbase = blockIdx.x * 64 + g * 8;
  const int myrow = rowbase + r8;
  const int b = myrow >> 11;    // uniform per block (64-row span, 64|2048)

  const float pos = tsteps[myrow];
  const float divs[8] = {1.0f, 0.74989421f, 0.56234133f, 0.42169650f,
                         0.31622777f, 0.23713737f, 0.17782794f, 0.13335214f};
  float emb[NE];
#pragma unroll
  for (int m = 0; m < 8; ++m) {
    float a = 48.0f * pos * divs[m];
    emb[2 * m] = sinf(a);
    emb[2 * m + 1] = cosf(a);
  }
  f32x2 q2[8];
#pragma unroll
  for (int e = 0; e < 8; ++e) {
    float a0 = bqs[2 * e], a1 = bqs[2 * e + 1];
#pragma unroll
    for (int i = 0; i < NE; ++i) {
      a0 += emb[i] * wqs[(2 * e) * NE + i];
      a1 += emb[i] * wqs[(2 * e + 1) * NE + i];
    }
    q2[e] = f32x2{a0, a1} * (0.25f * LOG2E);  // fold 1/sqrt(E), log2e
  }
  float* __restrict__ pld = &plds[wave][0][0];
  const int lb = lane & ~7;  // group's lane 0 (== g*8)
  const float* __restrict__ vb = val + (size_t)b * NK * 64;

  f32x2 acc2[8][4];
#pragma unroll
  for (int m = 0; m < 8; ++m)
#pragma unroll
    for (int d = 0; d < 4; ++d) acc2[m][d] = f32x2{0.f, 0.f};
  float lsum = 0.f;

  const int khi = wave;  // this wave's 64-key block
  for (int sp = 0; sp < 8; ++sp) {
    // phase 1: 8 scores for this lane's row (kt loads pipeline freely)
    float pown[8];
#pragma unroll
    for (int i = 0; i < 8; ++i) {
      const int ii = (sp * 8 + i + g * 8) & 63;  // group stagger
      const int k = (khi << 6) | ii;
      const float4* kr = (const float4*)(ktab + (size_t)k * NE);
      const float4 k0 = kr[0], k1 = kr[1], k2 = kr[2], k3 = kr[3];
      f32x2 s2 = {0.f, 0.f};
      s2 = __builtin_elementwise_fma(q2[0], f32x2{k0.x, k0.y}, s2);
      s2 = __builtin_elementwise_fma(q2[1], f32x2{k0.z, k0.w}, s2);
      s2 = __builtin_elementwise_fma(q2[2], f32x2{k1.x, k1.y}, s2);
      s2 = __builtin_elementwise_fma(q2[3], f32x2{k1.z, k1.w}, s2);
      s2 = __builtin_elementwise_fma(q2[4], f32x2{k2.x, k2.y}, s2);
      s2 = __builtin_elementwise_fma(q2[5], f32x2{k2.z, k2.w}, s2);
      s2 = __builtin_elementwise_fma(q2[6], f32x2{k3.x, k3.y}, s2);
      s2 = __builtin_elementwise_fma(q2[7], f32x2{k3.z, k3.w}, s2);
      const float p = __builtin_amdgcn_exp2f(s2.x + s2.y);  // O(1) scores
      pown[i] = p;
      lsum += p;
    }
    // phase 2a: publish 8 p's (lane-consecutive writes, conflict-free)
#pragma unroll
    for (int i = 0; i < 8; ++i) pld[i * 64 + lane] = pown[i];
    // phase 2b: PV over the 8 keys; v-loads + broadcast p-reads pipeline
#pragma unroll
    for (int i = 0; i < 8; ++i) {
      const int ii = (sp * 8 + i + g * 8) & 63;
      const int k = (khi << 6) | ii;
      const float* vr = vb + (size_t)k * 64 + r8 * 8;
      const float4 va = *(const float4*)(vr);
      const float4 vb4 = *(const float4*)(vr + 4);
      const float4 pq0 = *(const float4*)&pld[i * 64 + lb];
      const float4 pq1 = *(const float4*)&pld[i * 64 + lb + 4];
      const f32x2 v2[4] = {f32x2{va.x, va.y}, f32x2{va.z, va.w},
                           f32x2{vb4.x, vb4.y}, f32x2{vb4.z, vb4.w}};
      const float pm[8] = {pq0.x, pq0.y, pq0.z, pq0.w,
                           pq1.x, pq1.y, pq1.z, pq1.w};
#pragma unroll
      for (int m = 0; m < 8; ++m) {
        const f32x2 pm2 = {pm[m], pm[m]};
        acc2[m][0] = __builtin_elementwise_fma(pm2, v2[0], acc2[m][0]);
        acc2[m][1] = __builtin_elementwise_fma(pm2, v2[1], acc2[m][1]);
        acc2[m][2] = __builtin_elementwise_fma(pm2, v2[2], acc2[m][2]);
        acc2[m][3] = __builtin_elementwise_fma(pm2, v2[3], acc2[m][3]);
      }
    }
  }

  // cross-wave combine: 8 partials per (row, dim); one row per round.
  lbuf[wave][lane] = lsum;
  float lt = 0.f;
  float* ob = att + (size_t)rowbase * 64 + r8 * 8;
#pragma unroll
  for (int mm = 0; mm < 8; ++mm) {
    *(float4*)&cbuf[wave][lane][0] =
        make_float4(acc2[mm][0].x, acc2[mm][0].y, acc2[mm][1].x, acc2[mm][1].y);
    *(float4*)&cbuf[wave][lane][4] =
        make_float4(acc2[mm][2].x, acc2[mm][2].y, acc2[mm][3].x, acc2[mm][3].y);
    __syncthreads();
    if (mm == 0) {
      lt = 0.f;
#pragma unroll
      for (int w = 0; w < 8; ++w) lt += lbuf[w][lane];
    }
    if (wave == 0) {
      float4 sa = *(const float4*)&cbuf[0][lane][0];
      float4 sb = *(const float4*)&cbuf[0][lane][4];
#pragma unroll
      for (int w = 1; w < 8; ++w) {
        const float4 ca = *(const float4*)&cbuf[w][lane][0];
        const float4 cb = *(const float4*)&cbuf[w][lane][4];
        sa.x += ca.x; sa.y += ca.y; sa.z += ca.z; sa.w += ca.w;
        sb.x += cb.x; sb.y += cb.y; sb.z += cb.z; sb.w += cb.w;
      }
      const float im = 1.0f / bperm(lb + mm, lt);
      *(float4*)(ob + mm * 64) =
          make_float4(sa.x * im, sa.y * im, sa.z * im, sa.w * im);
      *(float4*)(ob + mm * 64 + 4) =
          make_float4(sb.x * im, sb.y * im, sb.z * im, sb.w * im);
    }
    __syncthreads();
  }
}

// Per-row MLP on folded weights, DS-lean (r15-proven).
__global__ __launch_bounds__(256) void mlp_kernel(
    const float* __restrict__ att,
    const float* __restrict__ w1p, const float* __restrict__ b1p,
    const float* __restrict__ W2, const float* __restrict__ b2,
    float* __restrict__ out) {
  __shared__ __align__(16) float w1s[NHID * 64];   // 12.8 KB
  __shared__ __align__(16) float w2s[NO * 52];     // 8.5 KB, 52-padded rows
  __shared__ float b1s[NHID], b2s[NO];
  const int tid = threadIdx.x;
  for (int i = tid; i < NHID * 64; i += 256) w1s[i] = w1p[i];
  for (int i = tid; i < NO * 52; i += 256) {
    const int oo = i / 52, o = i - oo * 52;
    w2s[i] = (o < NHID) ? W2[oo * NHID + o] : 0.f;
  }
  if (tid < NHID) b1s[tid] = b1p[tid];
  if (tid < NO) b2s[tid] = b2[tid];
  __syncthreads();

  const int row = blockIdx.x * 256 + tid;
  float ar[64];
  const float4* a4 = (const float4*)(att + (size_t)row * 64);
#pragma unroll
  for (int d4 = 0; d4 < 16; ++d4) {
    float4 v = a4[d4];
    ar[d4 * 4 + 0] = v.x;
    ar[d4 * 4 + 1] = v.y;
    ar[d4 * 4 + 2] = v.z;
    ar[d4 * 4 + 3] = v.w;
  }
  float h[52];
#pragma unroll 2
  for (int o = 0; o < NHID; ++o) {
    float acc = b1s[o];
    const float4* w4 = (const float4*)&w1s[o * 64];
#pragma unroll
    for (int i4 = 0; i4 < 16; ++i4) {
      float4 ww = w4[i4];
      acc += ar[i4 * 4 + 0] * ww.x + ar[i4 * 4 + 1] * ww.y +
             ar[i4 * 4 + 2] * ww.z + ar[i4 * 4 + 3] * ww.w;
    }
    h[o] = fmaxf(acc, 0.f);
  }
  h[50] = 0.f;
  h[51] = 0.f;
  float* orow = out + (size_t)row * NO;
#pragma unroll 2
  for (int oo = 0; oo < NO; ++oo) {
    float acc = b2s[oo];
    const float4* w4 = (const float4*)&w2s[oo * 52];
#pragma unroll
    for (int i4 = 0; i4 < 13; ++i4) {
      float4 ww = w4[i4];
      acc += h[i4 * 4 + 0] * ww.x + h[i4 * 4 + 1] * ww.y +
             h[i4 * 4 + 2] * ww.z + h[i4 * 4 + 3] * ww.w;
    }
    orow[oo] = acc;
  }
}

extern "C" void kernel_launch(void* const* d_in, const int* in_sizes, int n_in,
                              void* d_out, int out_size, void* d_ws, size_t ws_size,
                              hipStream_t stream) {
  const float* z = (const float*)d_in[0];
  const float* ts = (const float*)d_in[1];
  const float* refq = (const float*)d_in[2];
  const float* Wih_f = (const float*)d_in[3];
  const float* Whh_f = (const float*)d_in[4];
  const float* bih_f = (const float*)d_in[5];
  const float* bhh_f = (const float*)d_in[6];
  const float* Wih_b = (const float*)d_in[7];
  const float* Whh_b = (const float*)d_in[8];
  const float* bih_b = (const float*)d_in[9];
  const float* bhh_b = (const float*)d_in[10];
  const float* Wq = (const float*)d_in[11];
  const float* bq = (const float*)d_in[12];
  const float* Wk = (const float*)d_in[13];
  const float* bk = (const float*)d_in[14];
  const float* Wv = (const float*)d_in[15];
  const float* bv = (const float*)d_in[16];
  const float* W1 = (const float*)d_in[17];
  const float* b1 = (const float*)d_in[18];
  const float* W2 = (const float*)d_in[19];
  const float* b2 = (const float*)d_in[20];

  float* ws = (float*)d_ws;
  float* gi = ws;               // 3,145,728 (overlaid with att)
  float* att = ws;              // 4,194,304
  float* val = ws + 4194304;    // 1,048,576
  float* ktab = ws + 5242880;   // 8,192
  float* w1p = ws + 5251072;    // 3,200
  float* b1p = ws + 5254272;    // 64
  float* out = (float*)d_out;

  prep_kernel<<<3, 256, 0, stream>>>(refq, Wk, bk, Wv, bv, W1, b1,
                                     ktab, w1p, b1p);
  prep_gi_kernel<<<128, 256, 0, stream>>>(z, Wih_f, bih_f, bhh_f,
                                          Wih_b, bih_b, bhh_b, gi);
  gru_kernel<<<32, 64, 0, stream>>>(gi, Whh_f, bhh_f, Whh_b, bhh_b, val);
  attn_core_kernel<<<1024, 512, 0, stream>>>(ts, ktab, val, Wq, bq, att);
  mlp_kernel<<<256, 256, 0, stream>>>(att, w1p, b1p, W2, b2, out);
}

// Round 18
// 336.986 us; speedup vs baseline: 1.2400x; 1.2400x over previous
//
#include <hip/hip_runtime.h>
#include <hip/hip_bf16.h>
#include <math.h>

#define NB 32
#define NQ 2048
#define NK 512
#define NE 16
#define NH 32
#define NL 20
#define NHID 50
#define NO 41

#define LOG2E 1.4426950408889634f
#define TWO_LOG2E 2.8853900817779268f

// ws layout (floats):
// gi   : [64][512][96] @ 0        (3,145,728)  OVERLAID with att (gru before attn)
// att  : [65536][64]   @ 0        (4,194,304)  normalized P@val (pre-Wv)
// val  : [32][512][64] @ 4194304  (1,048,576)
// ktab : [512][16]     @ 5242880  (8,192)
// w1p  : [50][64]      @ 5251072  (3,200)      W1 @ Wv
// b1p  : [50]          @ 5254272  (64)         b1 + W1 @ bv
// total ~21.0 MB (proven size)

typedef __attribute__((ext_vector_type(2))) float f32x2;

__device__ __forceinline__ float bperm(int lane, float v) {
  return __builtin_bit_cast(
      float, __builtin_amdgcn_ds_bpermute(lane << 2, __builtin_bit_cast(int, v)));
}

// Merged prep: blocks 0-1 k-table; block 2 fold Wv into W1; blocks 3-130
// input-side GRU gates (pre-scaled for exp2 activations).
__global__ __launch_bounds__(256) void prep_all_kernel(
    const float* __restrict__ refq, const float* __restrict__ Wk,
    const float* __restrict__ bk,
    const float* __restrict__ Wv, const float* __restrict__ bv,
    const float* __restrict__ W1, const float* __restrict__ b1,
    const float* __restrict__ z,
    const float* __restrict__ Wih_f, const float* __restrict__ bih_f,
    const float* __restrict__ bhh_f,
    const float* __restrict__ Wih_b, const float* __restrict__ bih_b,
    const float* __restrict__ bhh_b,
    float* __restrict__ ktab, float* __restrict__ w1p,
    float* __restrict__ b1p, float* __restrict__ gi) {
  const int tid = threadIdx.x;
  const int bid = blockIdx.x;
  if (bid < 2) {
    const int r = bid * 256 + tid;
    const float divs[8] = {1.0f, 0.74989421f, 0.56234133f, 0.42169650f,
                           0.31622777f, 0.23713737f, 0.17782794f, 0.13335214f};
    float pos = refq[r];
    float emb[NE];
#pragma unroll
    for (int m = 0; m < 8; ++m) {
      float a = 48.0f * pos * divs[m];
      emb[2 * m] = sinf(a);
      emb[2 * m + 1] = cosf(a);
    }
#pragma unroll
    for (int e = 0; e < NE; ++e) {
      float acc = bk[e];
#pragma unroll
      for (int i = 0; i < NE; ++i) acc += emb[i] * Wk[e * NE + i];
      ktab[r * NE + e] = acc;
    }
  } else if (bid == 2) {
    for (int e = tid; e < NHID * 64; e += 256) {
      const int o = e >> 6, i = e & 63;
      float acc = 0.f;
#pragma unroll 4
      for (int d = 0; d < 64; ++d) acc += W1[o * 64 + d] * Wv[d * 64 + i];
      w1p[e] = acc;
    }
    if (tid < NHID) {
      float acc = b1[tid];
#pragma unroll 4
      for (int d = 0; d < 64; ++d) acc += W1[tid * 64 + d] * bv[d];
      b1p[tid] = acc;
    }
  } else {
    const int row = (bid - 3) * 256 + tid;  // chain*512 + t
    const int c = row >> 9, t = row & 511;
    const int dir = c >> 5, b = c & 31;
    const float* __restrict__ Wih = dir ? Wih_b : Wih_f;
    const float* __restrict__ bih = dir ? bih_b : bih_f;
    const float* __restrict__ bhh = dir ? bhh_b : bhh_f;
    const float* __restrict__ zr = z + ((size_t)b * NK + t) * NL;
    float x[NL];
#pragma unroll
    for (int i = 0; i < NL; ++i) x[i] = zr[i];
    float* __restrict__ go = gi + (size_t)row * 96;
    for (int g = 0; g < 96; ++g) {
      float acc = bih[g] + (g < 64 ? bhh[g] : 0.f);
#pragma unroll
      for (int i = 0; i < NL; ++i) acc += x[i] * Wih[g * NL + i];
      go[g] = acc * (g < 64 ? LOG2E : TWO_LOG2E);
    }
  }
}

// Serial GRU (round-13, PASSED at 134 us): 2 chains per wave, full 32-dots,
// ONE DS round per step, exp2-folded activations, pk-FMA, pointer-walked IO.
__global__ __launch_bounds__(64) void gru_kernel(
    const float* __restrict__ gi,
    const float* __restrict__ Whh_f, const float* __restrict__ bhh_f,
    const float* __restrict__ Whh_b, const float* __restrict__ bhh_b,
    float* __restrict__ val) {
  __shared__ __align__(16) float hbuf[64];  // [chain-half][32]
  const int l = threadIdx.x;
  const int j = l & 31, half = l >> 5;
  const int c = blockIdx.x * 2 + half;   // 2|32 => both halves same dir
  const int dir = c >> 5, b = c & 31;
  const int hb = half * 32;
  const float* __restrict__ Whh = dir ? Whh_b : Whh_f;
  const float* __restrict__ bhh = dir ? bhh_b : bhh_f;

  // weights pre-scaled: r,z x log2e; n x 2*log2e (gi scaled to match)
  f32x2 wr[16], wz[16], wn[16];
#pragma unroll
  for (int i = 0; i < 16; ++i) {
    wr[i] = f32x2{Whh[j * 32 + 2 * i], Whh[j * 32 + 2 * i + 1]} * LOG2E;
    wz[i] = f32x2{Whh[(j + 32) * 32 + 2 * i], Whh[(j + 32) * 32 + 2 * i + 1]} *
            LOG2E;
    wn[i] = f32x2{Whh[(j + 64) * 32 + 2 * i], Whh[(j + 64) * 32 + 2 * i + 1]} *
            TWO_LOG2E;
  }
  const float bhn = bhh[j + 64] * TWO_LOG2E;
  float h = 0.f;
  hbuf[l] = 0.f;

  const float* __restrict__ gic = gi + (size_t)c * NK * 96;
  const int gstart = dir ? (NK - 1) * 96 : 0;
  const int gstride = dir ? -96 : 96;
  float* __restrict__ vp =
      val + ((size_t)b * NK + (dir ? NK - 1 : 0)) * 64 + dir * 32 + j;
  const int vstride = dir ? -64 : 64;

  float r0, z0, n0, r1, z1, n1, r2, z2, n2, r3, z3, n3;
  int gidx = gstart;
  auto giload = [&](float& gr, float& gz, float& gn) {
    const float* p = gic + gidx;
    gr = p[j];
    gz = p[32 + j];
    gn = p[64 + j];
    gidx += gstride;
  };
  giload(r0, z0, n0);
  giload(r1, z1, n1);
  giload(r2, z2, n2);
  giload(r3, z3, n3);

  auto step = [&](bool pf, float& gr, float& gz, float& gn) {
    const float gir = gr, giz = gz, gin = gn;
    if (pf) giload(gr, gz, gn);  // global prefetch (vmcnt queue)
    hbuf[l] = h;  // same-wave LDS is in-order (proven rounds 4-17)
    f32x2 hv[16];
#pragma unroll
    for (int t = 0; t < 4; ++t) {
      const float4 hq = *(const float4*)&hbuf[hb + t * 8];
      const float4 hq2 = *(const float4*)&hbuf[hb + t * 8 + 4];
      hv[t * 4 + 0] = f32x2{hq.x, hq.y};
      hv[t * 4 + 1] = f32x2{hq.z, hq.w};
      hv[t * 4 + 2] = f32x2{hq2.x, hq2.y};
      hv[t * 4 + 3] = f32x2{hq2.z, hq2.w};
    }
    f32x2 sr2 = {0.f, 0.f}, sz2 = {0.f, 0.f}, sn2 = {0.f, 0.f};
    f32x2 sr3 = {0.f, 0.f}, sz3 = {0.f, 0.f}, sn3 = {0.f, 0.f};
#pragma unroll
    for (int t = 0; t < 8; ++t) {
      sr2 = __builtin_elementwise_fma(wr[t], hv[t], sr2);
      sz2 = __builtin_elementwise_fma(wz[t], hv[t], sz2);
      sn2 = __builtin_elementwise_fma(wn[t], hv[t], sn2);
      sr3 = __builtin_elementwise_fma(wr[8 + t], hv[8 + t], sr3);
      sz3 = __builtin_elementwise_fma(wz[8 + t], hv[8 + t], sz3);
      sn3 = __builtin_elementwise_fma(wn[8 + t], hv[8 + t], sn3);
    }
    const float sr = (sr2.x + sr2.y) + (sr3.x + sr3.y);
    const float sz = (sz2.x + sz2.y) + (sz3.x + sz3.y);
    const float sn = (sn2.x + sn2.y) + (sn3.x + sn3.y);
    const float rg =
        __builtin_amdgcn_rcpf(1.0f + __builtin_amdgcn_exp2f(-(gir + sr)));
    const float ug =
        __builtin_amdgcn_rcpf(1.0f + __builtin_amdgcn_exp2f(-(giz + sz)));
    const float ng =
        1.0f - 2.0f * __builtin_amdgcn_rcpf(
                          __builtin_amdgcn_exp2f(gin + rg * (sn + bhn)) + 1.0f);
    h = ng + ug * (h - ng);
    *vp = h;
    vp += vstride;
  };
  for (int s = 0; s < NK; s += 4) {
    step(s + 4 < NK, r0, z0, n0);
    step(s + 5 < NK, r1, z1, n1);
    step(s + 6 < NK, r2, z2, n2);
    step(s + 7 < NK, r3, z3, n3);
  }
}

// R=8 attention v7 = r15-v4 (PASSED, 133.6 us) + 1-deep v-prefetch with
// ping-pong unroll-2: key i+1's v float4s issue at the top of iteration i
// into alternating register pairs, consumed next sub-iteration (no same-iter
// waitcnt). kt from global (L1-resident), p-share via per-wave LDS slot,
// 4 waves/block over k-quarters, LDS combine.
__global__ __launch_bounds__(256) void attn_core_kernel(
    const float* __restrict__ tsteps, const float* __restrict__ ktab,
    const float* __restrict__ val,
    const float* __restrict__ Wq, const float* __restrict__ bq,
    float* __restrict__ att) {
  __shared__ __align__(16) float cbuf[4][64][16];    // 16 KB combine buffer
  __shared__ __align__(16) float pbuf[256];          // 1 KB p-share
  __shared__ float lbuf[4][64];                      // 1 KB lsum partials
  __shared__ float wqs[NE * NE];
  __shared__ float bqs[NE];
  const int tid = threadIdx.x;
  for (int i = tid; i < NE * NE; i += 256) wqs[i] = Wq[i];
  if (tid < NE) bqs[tid] = bq[tid];
  __syncthreads();

  const int lane = tid & 63;
  const int g = lane >> 3;      // group 0..7
  const int r8 = lane & 7;      // row-in-group for scoring; d-eighth for acc
  const int wave = tid >> 6;    // k-quarter owner
  const int rowbase = blockIdx.x * 64 + g * 8;
  const int myrow = rowbase + r8;
  const int b = myrow >> 11;    // uniform per block (64-row span, 64|2048)

  const float pos = tsteps[myrow];
  const float divs[8] = {1.0f, 0.74989421f, 0.56234133f, 0.42169650f,
                         0.31622777f, 0.23713737f, 0.17782794f, 0.13335214f};
  float emb[NE];
#pragma unroll
  for (int m = 0; m < 8; ++m) {
    float a = 48.0f * pos * divs[m];
    emb[2 * m] = sinf(a);
    emb[2 * m + 1] = cosf(a);
  }
  float q[NE];
#pragma unroll
  for (int e = 0; e < NE; ++e) {
    float acc = bqs[e];
#pragma unroll
    for (int i = 0; i < NE; ++i) acc += emb[i] * wqs[e * NE + i];
    q[e] = acc * (0.25f * LOG2E);  // fold 1/sqrt(E) and log2e (exp2 direct)
  }
  const int pbase = tid & ~7;  // this wave's group slot in pbuf
  const float* __restrict__ vb = val + (size_t)b * NK * 64;

  float acc[8][8];
#pragma unroll
  for (int m = 0; m < 8; ++m)
#pragma unroll
    for (int d = 0; d < 8; ++d) acc[m][d] = 0.f;
  float lsum = 0.f;

  // flat key index i in [0,128): khi = (wave<<1)|(i>>6), ii = ((i&63)+g*8)&63
  auto kidx = [&](int i) {
    const int khi = (wave << 1) | (i >> 6);
    const int ii = ((i & 63) + g * 8) & 63;
    return (khi << 6) | ii;
  };
  auto body = [&](int i, const float4& va, const float4& vb4) {
    const int k = kidx(i);
    const float4* kr = (const float4*)(ktab + (size_t)k * NE);  // L1-resident
    const float4 k0 = kr[0], k1 = kr[1], k2 = kr[2], k3 = kr[3];
    float s;
    s  = q[0] * k0.x + q[1] * k0.y + q[2] * k0.z + q[3] * k0.w;
    s += q[4] * k1.x + q[5] * k1.y + q[6] * k1.z + q[7] * k1.w;
    s += q[8] * k2.x + q[9] * k2.y + q[10] * k2.z + q[11] * k2.w;
    s += q[12] * k3.x + q[13] * k3.y + q[14] * k3.z + q[15] * k3.w;
    const float p = __builtin_amdgcn_exp2f(s);  // scores O(1): no max-sub
    lsum += p;
    pbuf[tid] = p;  // same-wave in-order LDS (proven rounds 4-17)
    const float4 pq0 = *(const float4*)&pbuf[pbase];
    const float4 pq1 = *(const float4*)&pbuf[pbase + 4];
    const float pm[8] = {pq0.x, pq0.y, pq0.z, pq0.w,
                         pq1.x, pq1.y, pq1.z, pq1.w};
#pragma unroll
    for (int m = 0; m < 8; ++m) {
      acc[m][0] += pm[m] * va.x;  acc[m][1] += pm[m] * va.y;
      acc[m][2] += pm[m] * va.z;  acc[m][3] += pm[m] * va.w;
      acc[m][4] += pm[m] * vb4.x; acc[m][5] += pm[m] * vb4.y;
      acc[m][6] += pm[m] * vb4.z; acc[m][7] += pm[m] * vb4.w;
    }
  };

  // ping-pong 1-deep v-prefetch
  const float* vr0 = vb + (size_t)kidx(0) * 64 + r8 * 8;
  float4 vA0 = *(const float4*)(vr0);
  float4 vB0 = *(const float4*)(vr0 + 4);
  float4 vA1, vB1;
  for (int i = 0; i < 128; i += 2) {
    {  // issue v[i+1] into buffer 1, then process key i from buffer 0
      const float* vrn = vb + (size_t)kidx(i + 1) * 64 + r8 * 8;
      vA1 = *(const float4*)(vrn);
      vB1 = *(const float4*)(vrn + 4);
      body(i, vA0, vB0);
    }
    {  // issue v[i+2] into buffer 0, then process key i+1 from buffer 1
      const int in2 = (i + 2 < 128) ? i + 2 : 127;
      const float* vrn = vb + (size_t)kidx(in2) * 64 + r8 * 8;
      vA0 = *(const float4*)(vrn);
      vB0 = *(const float4*)(vrn + 4);
      body(i + 1, vA1, vB1);
    }
  }

  // cross-wave combine: 4 partials per (row, dim); lsum totals once.
  const int lb = lane & ~7;
  lbuf[wave][lane] = lsum;
  float lt = 0.f;
  float* ob = att + (size_t)rowbase * 64 + r8 * 8;
#pragma unroll
  for (int mm = 0; mm < 8; mm += 2) {
    *(float4*)&cbuf[wave][lane][0] =
        make_float4(acc[mm][0], acc[mm][1], acc[mm][2], acc[mm][3]);
    *(float4*)&cbuf[wave][lane][4] =
        make_float4(acc[mm][4], acc[mm][5], acc[mm][6], acc[mm][7]);
    *(float4*)&cbuf[wave][lane][8] =
        make_float4(acc[mm + 1][0], acc[mm + 1][1], acc[mm + 1][2],
                    acc[mm + 1][3]);
    *(float4*)&cbuf[wave][lane][12] =
        make_float4(acc[mm + 1][4], acc[mm + 1][5], acc[mm + 1][6],
                    acc[mm + 1][7]);
    __syncthreads();
    if (mm == 0)
      lt = lbuf[0][lane] + lbuf[1][lane] + lbuf[2][lane] + lbuf[3][lane];
    if (wave == 0) {
      float s[16];
#pragma unroll
      for (int d4 = 0; d4 < 4; ++d4) {
        const float4 c0 = *(const float4*)&cbuf[0][lane][d4 * 4];
        const float4 c1 = *(const float4*)&cbuf[1][lane][d4 * 4];
        const float4 c2 = *(const float4*)&cbuf[2][lane][d4 * 4];
        const float4 c3 = *(const float4*)&cbuf[3][lane][d4 * 4];
        s[d4 * 4 + 0] = c0.x + c1.x + c2.x + c3.x;
        s[d4 * 4 + 1] = c0.y + c1.y + c2.y + c3.y;
        s[d4 * 4 + 2] = c0.z + c1.z + c2.z + c3.z;
        s[d4 * 4 + 3] = c0.w + c1.w + c2.w + c3.w;
      }
      const float im0 = 1.0f / bperm(lb + mm, lt);
      const float im1 = 1.0f / bperm(lb + mm + 1, lt);
      *(float4*)(ob + mm * 64) =
          make_float4(s[0] * im0, s[1] * im0, s[2] * im0, s[3] * im0);
      *(float4*)(ob + mm * 64 + 4) =
          make_float4(s[4] * im0, s[5] * im0, s[6] * im0, s[7] * im0);
      *(float4*)(ob + (mm + 1) * 64) =
          make_float4(s[8] * im1, s[9] * im1, s[10] * im1, s[11] * im1);
      *(float4*)(ob + (mm + 1) * 64 + 4) =
          make_float4(s[12] * im1, s[13] * im1, s[14] * im1, s[15] * im1);
    }
    __syncthreads();
  }
}

// Per-row MLP on folded weights, DS-lean (r15-proven).
__global__ __launch_bounds__(256) void mlp_kernel(
    const float* __restrict__ att,
    const float* __restrict__ w1p, const float* __restrict__ b1p,
    const float* __restrict__ W2, const float* __restrict__ b2,
    float* __restrict__ out) {
  __shared__ __align__(16) float w1s[NHID * 64];   // 12.8 KB
  __shared__ __align__(16) float w2s[NO * 52];     // 8.5 KB, 52-padded rows
  __shared__ float b1s[NHID], b2s[NO];
  const int tid = threadIdx.x;
  for (int i = tid; i < NHID * 64; i += 256) w1s[i] = w1p[i];
  for (int i = tid; i < NO * 52; i += 256) {
    const int oo = i / 52, o = i - oo * 52;
    w2s[i] = (o < NHID) ? W2[oo * NHID + o] : 0.f;
  }
  if (tid < NHID) b1s[tid] = b1p[tid];
  if (tid < NO) b2s[tid] = b2[tid];
  __syncthreads();

  const int row = blockIdx.x * 256 + tid;
  float ar[64];
  const float4* a4 = (const float4*)(att + (size_t)row * 64);
#pragma unroll
  for (int d4 = 0; d4 < 16; ++d4) {
    float4 v = a4[d4];
    ar[d4 * 4 + 0] = v.x;
    ar[d4 * 4 + 1] = v.y;
    ar[d4 * 4 + 2] = v.z;
    ar[d4 * 4 + 3] = v.w;
  }
  float h[52];
#pragma unroll 2
  for (int o = 0; o < NHID; ++o) {
    float acc = b1s[o];
    const float4* w4 = (const float4*)&w1s[o * 64];
#pragma unroll
    for (int i4 = 0; i4 < 16; ++i4) {
      float4 ww = w4[i4];
      acc += ar[i4 * 4 + 0] * ww.x + ar[i4 * 4 + 1] * ww.y +
             ar[i4 * 4 + 2] * ww.z + ar[i4 * 4 + 3] * ww.w;
    }
    h[o] = fmaxf(acc, 0.f);
  }
  h[50] = 0.f;
  h[51] = 0.f;
  float* orow = out + (size_t)row * NO;
#pragma unroll 2
  for (int oo = 0; oo < NO; ++oo) {
    float acc = b2s[oo];
    const float4* w4 = (const float4*)&w2s[oo * 52];
#pragma unroll
    for (int i4 = 0; i4 < 13; ++i4) {
      float4 ww = w4[i4];
      acc += h[i4 * 4 + 0] * ww.x + h[i4 * 4 + 1] * ww.y +
             h[i4 * 4 + 2] * ww.z + h[i4 * 4 + 3] * ww.w;
    }
    orow[oo] = acc;
  }
}

extern "C" void kernel_launch(void* const* d_in, const int* in_sizes, int n_in,
                              void* d_out, int out_size, void* d_ws, size_t ws_size,
                              hipStream_t stream) {
  const float* z = (const float*)d_in[0];
  const float* ts = (const float*)d_in[1];
  const float* refq = (const float*)d_in[2];
  const float* Wih_f = (const float*)d_in[3];
  const float* Whh_f = (const float*)d_in[4];
  const float* bih_f = (const float*)d_in[5];
  const float* bhh_f = (const float*)d_in[6];
  const float* Wih_b = (const float*)d_in[7];
  const float* Whh_b = (const float*)d_in[8];
  const float* bih_b = (const float*)d_in[9];
  const float* bhh_b = (const float*)d_in[10];
  const float* Wq = (const float*)d_in[11];
  const float* bq = (const float*)d_in[12];
  const float* Wk = (const float*)d_in[13];
  const float* bk = (const float*)d_in[14];
  const float* Wv = (const float*)d_in[15];
  const float* bv = (const float*)d_in[16];
  const float* W1 = (const float*)d_in[17];
  const float* b1 = (const float*)d_in[18];
  const float* W2 = (const float*)d_in[19];
  const float* b2 = (const float*)d_in[20];

  float* ws = (float*)d_ws;
  float* gi = ws;               // 3,145,728 (overlaid with att)
  float* att = ws;              // 4,194,304
  float* val = ws + 4194304;    // 1,048,576
  float* ktab = ws + 5242880;   // 8,192
  float* w1p = ws + 5251072;    // 3,200
  float* b1p = ws + 5254272;    // 64
  float* out = (float*)d_out;

  prep_all_kernel<<<131, 256, 0, stream>>>(
      refq, Wk, bk, Wv, bv, W1, b1, z, Wih_f, bih_f, bhh_f, Wih_b, bih_b,
      bhh_b, ktab, w1p, b1p, gi);
  gru_kernel<<<32, 64, 0, stream>>>(gi, Whh_f, bhh_f, Whh_b, bhh_b, val);
  attn_core_kernel<<<1024, 256, 0, stream>>>(ts, ktab, val, Wq, bq, att);
  mlp_kernel<<<256, 256, 0, stream>>>(att, w1p, b1p, W2, b2, out);
}

// Round 19
// 322.350 us; speedup vs baseline: 1.2963x; 1.0454x over previous
//
#include <hip/hip_runtime.h>
#include <hip/hip_bf16.h>
#include <math.h>

#define NB 32
#define NQ 2048
#define NK 512
#define NE 16
#define NH 32
#define NL 20
#define NHID 50
#define NO 41

#define LOG2E 1.4426950408889634f
#define TWO_LOG2E 2.8853900817779268f

// ws layout (floats):
// gi   : [64][512][96] @ 0        (3,145,728)  OVERLAID with att (gru before attn)
// att  : [65536][64]   @ 0        (4,194,304)  normalized P@val (pre-Wv)
// val  : [32][512][64] @ 4194304  (1,048,576)
// ktab : [512][16]     @ 5242880  (8,192)
// w1p  : [50][64]      @ 5251072  (3,200)      W1 @ Wv
// b1p  : [50]          @ 5254272  (64)         b1 + W1 @ bv
// total ~21.0 MB (proven size)

typedef __attribute__((ext_vector_type(2))) float f32x2;

__device__ __forceinline__ float bperm(int lane, float v) {
  return __builtin_bit_cast(
      float, __builtin_amdgcn_ds_bpermute(lane << 2, __builtin_bit_cast(int, v)));
}

// Merged prep (r18-proven): blocks 0-1 k-table; block 2 fold Wv into W1;
// blocks 3-130 input-side GRU gates (pre-scaled for exp2 activations).
__global__ __launch_bounds__(256) void prep_all_kernel(
    const float* __restrict__ refq, const float* __restrict__ Wk,
    const float* __restrict__ bk,
    const float* __restrict__ Wv, const float* __restrict__ bv,
    const float* __restrict__ W1, const float* __restrict__ b1,
    const float* __restrict__ z,
    const float* __restrict__ Wih_f, const float* __restrict__ bih_f,
    const float* __restrict__ bhh_f,
    const float* __restrict__ Wih_b, const float* __restrict__ bih_b,
    const float* __restrict__ bhh_b,
    float* __restrict__ ktab, float* __restrict__ w1p,
    float* __restrict__ b1p, float* __restrict__ gi) {
  const int tid = threadIdx.x;
  const int bid = blockIdx.x;
  if (bid < 2) {
    const int r = bid * 256 + tid;
    const float divs[8] = {1.0f, 0.74989421f, 0.56234133f, 0.42169650f,
                           0.31622777f, 0.23713737f, 0.17782794f, 0.13335214f};
    float pos = refq[r];
    float emb[NE];
#pragma unroll
    for (int m = 0; m < 8; ++m) {
      float a = 48.0f * pos * divs[m];
      emb[2 * m] = sinf(a);
      emb[2 * m + 1] = cosf(a);
    }
#pragma unroll
    for (int e = 0; e < NE; ++e) {
      float acc = bk[e];
#pragma unroll
      for (int i = 0; i < NE; ++i) acc += emb[i] * Wk[e * NE + i];
      ktab[r * NE + e] = acc;
    }
  } else if (bid == 2) {
    for (int e = tid; e < NHID * 64; e += 256) {
      const int o = e >> 6, i = e & 63;
      float acc = 0.f;
#pragma unroll 4
      for (int d = 0; d < 64; ++d) acc += W1[o * 64 + d] * Wv[d * 64 + i];
      w1p[e] = acc;
    }
    if (tid < NHID) {
      float acc = b1[tid];
#pragma unroll 4
      for (int d = 0; d < 64; ++d) acc += W1[tid * 64 + d] * bv[d];
      b1p[tid] = acc;
    }
  } else {
    const int row = (bid - 3) * 256 + tid;  // chain*512 + t
    const int c = row >> 9, t = row & 511;
    const int dir = c >> 5, b = c & 31;
    const float* __restrict__ Wih = dir ? Wih_b : Wih_f;
    const float* __restrict__ bih = dir ? bih_b : bih_f;
    const float* __restrict__ bhh = dir ? bhh_b : bhh_f;
    const float* __restrict__ zr = z + ((size_t)b * NK + t) * NL;
    float x[NL];
#pragma unroll
    for (int i = 0; i < NL; ++i) x[i] = zr[i];
    float* __restrict__ go = gi + (size_t)row * 96;
    for (int g = 0; g < 96; ++g) {
      float acc = bih[g] + (g < 64 ? bhh[g] : 0.f);
#pragma unroll
      for (int i = 0; i < NL; ++i) acc += x[i] * Wih[g * NL + i];
      go[g] = acc * (g < 64 ? LOG2E : TWO_LOG2E);
    }
  }
}

// Serial GRU (round-13, PASSED at 134 us): 2 chains per wave, full 32-dots,
// ONE DS round per step, exp2-folded activations, pk-FMA, pointer-walked IO.
__global__ __launch_bounds__(64) void gru_kernel(
    const float* __restrict__ gi,
    const float* __restrict__ Whh_f, const float* __restrict__ bhh_f,
    const float* __restrict__ Whh_b, const float* __restrict__ bhh_b,
    float* __restrict__ val) {
  __shared__ __align__(16) float hbuf[64];  // [chain-half][32]
  const int l = threadIdx.x;
  const int j = l & 31, half = l >> 5;
  const int c = blockIdx.x * 2 + half;   // 2|32 => both halves same dir
  const int dir = c >> 5, b = c & 31;
  const int hb = half * 32;
  const float* __restrict__ Whh = dir ? Whh_b : Whh_f;
  const float* __restrict__ bhh = dir ? bhh_b : bhh_f;

  // weights pre-scaled: r,z x log2e; n x 2*log2e (gi scaled to match)
  f32x2 wr[16], wz[16], wn[16];
#pragma unroll
  for (int i = 0; i < 16; ++i) {
    wr[i] = f32x2{Whh[j * 32 + 2 * i], Whh[j * 32 + 2 * i + 1]} * LOG2E;
    wz[i] = f32x2{Whh[(j + 32) * 32 + 2 * i], Whh[(j + 32) * 32 + 2 * i + 1]} *
            LOG2E;
    wn[i] = f32x2{Whh[(j + 64) * 32 + 2 * i], Whh[(j + 64) * 32 + 2 * i + 1]} *
            TWO_LOG2E;
  }
  const float bhn = bhh[j + 64] * TWO_LOG2E;
  float h = 0.f;
  hbuf[l] = 0.f;

  const float* __restrict__ gic = gi + (size_t)c * NK * 96;
  const int gstart = dir ? (NK - 1) * 96 : 0;
  const int gstride = dir ? -96 : 96;
  float* __restrict__ vp =
      val + ((size_t)b * NK + (dir ? NK - 1 : 0)) * 64 + dir * 32 + j;
  const int vstride = dir ? -64 : 64;

  float r0, z0, n0, r1, z1, n1, r2, z2, n2, r3, z3, n3;
  int gidx = gstart;
  auto giload = [&](float& gr, float& gz, float& gn) {
    const float* p = gic + gidx;
    gr = p[j];
    gz = p[32 + j];
    gn = p[64 + j];
    gidx += gstride;
  };
  giload(r0, z0, n0);
  giload(r1, z1, n1);
  giload(r2, z2, n2);
  giload(r3, z3, n3);

  auto step = [&](bool pf, float& gr, float& gz, float& gn) {
    const float gir = gr, giz = gz, gin = gn;
    if (pf) giload(gr, gz, gn);  // global prefetch (vmcnt queue)
    hbuf[l] = h;  // same-wave LDS is in-order (proven rounds 4-18)
    f32x2 hv[16];
#pragma unroll
    for (int t = 0; t < 4; ++t) {
      const float4 hq = *(const float4*)&hbuf[hb + t * 8];
      const float4 hq2 = *(const float4*)&hbuf[hb + t * 8 + 4];
      hv[t * 4 + 0] = f32x2{hq.x, hq.y};
      hv[t * 4 + 1] = f32x2{hq.z, hq.w};
      hv[t * 4 + 2] = f32x2{hq2.x, hq2.y};
      hv[t * 4 + 3] = f32x2{hq2.z, hq2.w};
    }
    f32x2 sr2 = {0.f, 0.f}, sz2 = {0.f, 0.f}, sn2 = {0.f, 0.f};
    f32x2 sr3 = {0.f, 0.f}, sz3 = {0.f, 0.f}, sn3 = {0.f, 0.f};
#pragma unroll
    for (int t = 0; t < 8; ++t) {
      sr2 = __builtin_elementwise_fma(wr[t], hv[t], sr2);
      sz2 = __builtin_elementwise_fma(wz[t], hv[t], sz2);
      sn2 = __builtin_elementwise_fma(wn[t], hv[t], sn2);
      sr3 = __builtin_elementwise_fma(wr[8 + t], hv[8 + t], sr3);
      sz3 = __builtin_elementwise_fma(wz[8 + t], hv[8 + t], sz3);
      sn3 = __builtin_elementwise_fma(wn[8 + t], hv[8 + t], sn3);
    }
    const float sr = (sr2.x + sr2.y) + (sr3.x + sr3.y);
    const float sz = (sz2.x + sz2.y) + (sz3.x + sz3.y);
    const float sn = (sn2.x + sn2.y) + (sn3.x + sn3.y);
    const float rg =
        __builtin_amdgcn_rcpf(1.0f + __builtin_amdgcn_exp2f(-(gir + sr)));
    const float ug =
        __builtin_amdgcn_rcpf(1.0f + __builtin_amdgcn_exp2f(-(giz + sz)));
    const float ng =
        1.0f - 2.0f * __builtin_amdgcn_rcpf(
                          __builtin_amdgcn_exp2f(gin + rg * (sn + bhn)) + 1.0f);
    h = ng + ug * (h - ng);
    *vp = h;
    vp += vstride;
  };
  for (int s = 0; s < NK; s += 4) {
    step(s + 4 < NK, r0, z0, n0);
    step(s + 5 < NK, r1, z1, n1);
    step(s + 6 < NK, r2, z2, n2);
    step(s + 7 < NK, r3, z3, n3);
  }
}

// R=8 attention v4 (r15, PASSED at 133.6 us — byte-exact revert): p-share
// via per-wave LDS slot (1 ds_write + 2 broadcast ds_read_b128); kt from
// global (L1-resident); 4 waves/block over k-quarters; LDS combine.
// No explicit prefetch: the compiler's own schedule beat ours (r18 lesson).
__global__ __launch_bounds__(256) void attn_core_kernel(
    const float* __restrict__ tsteps, const float* __restrict__ ktab,
    const float* __restrict__ val,
    const float* __restrict__ Wq, const float* __restrict__ bq,
    float* __restrict__ att) {
  __shared__ __align__(16) float cbuf[4][64][16];    // 16 KB combine buffer
  __shared__ __align__(16) float pbuf[256];          // 1 KB p-share
  __shared__ float lbuf[4][64];                      // 1 KB lsum partials
  __shared__ float wqs[NE * NE];
  __shared__ float bqs[NE];
  const int tid = threadIdx.x;
  for (int i = tid; i < NE * NE; i += 256) wqs[i] = Wq[i];
  if (tid < NE) bqs[tid] = bq[tid];
  __syncthreads();

  const int lane = tid & 63;
  const int g = lane >> 3;      // group 0..7
  const int r8 = lane & 7;      // row-in-group for scoring; d-eighth for acc
  const int wave = tid >> 6;    // k-quarter owner
  const int rowbase = blockIdx.x * 64 + g * 8;
  const int myrow = rowbase + r8;
  const int b = myrow >> 11;    // uniform per block (64-row span, 64|2048)

  const float pos = tsteps[myrow];
  const float divs[8] = {1.0f, 0.74989421f, 0.56234133f, 0.42169650f,
                         0.31622777f, 0.23713737f, 0.17782794f, 0.13335214f};
  float emb[NE];
#pragma unroll
  for (int m = 0; m < 8; ++m) {
    float a = 48.0f * pos * divs[m];
    emb[2 * m] = sinf(a);
    emb[2 * m + 1] = cosf(a);
  }
  float q[NE];
#pragma unroll
  for (int e = 0; e < NE; ++e) {
    float acc = bqs[e];
#pragma unroll
    for (int i = 0; i < NE; ++i) acc += emb[i] * wqs[e * NE + i];
    q[e] = acc * (0.25f * LOG2E);  // fold 1/sqrt(E) and log2e (exp2 direct)
  }
  const int pbase = tid & ~7;  // this wave's group slot in pbuf
  const float* __restrict__ vb = val + (size_t)b * NK * 64;

  float acc[8][8];
#pragma unroll
  for (int m = 0; m < 8; ++m)
#pragma unroll
    for (int d = 0; d < 8; ++d) acc[m][d] = 0.f;
  float lsum = 0.f;

#pragma unroll
  for (int kb = 0; kb < 2; ++kb) {
    const int khi = (wave << 1) | kb;   // this wave's k-block (uniform)
#pragma unroll 2
    for (int i = 0; i < 64; ++i) {
      const int ii = (i + g * 8) & 63;  // group stagger: distinct rows/instr
      const int k = (khi << 6) | ii;
      const float4* kr = (const float4*)(ktab + (size_t)k * NE);
      const float4 k0 = kr[0], k1 = kr[1], k2 = kr[2], k3 = kr[3];
      float s;
      s  = q[0] * k0.x + q[1] * k0.y + q[2] * k0.z + q[3] * k0.w;
      s += q[4] * k1.x + q[5] * k1.y + q[6] * k1.z + q[7] * k1.w;
      s += q[8] * k2.x + q[9] * k2.y + q[10] * k2.z + q[11] * k2.w;
      s += q[12] * k3.x + q[13] * k3.y + q[14] * k3.z + q[15] * k3.w;
      const float p = __builtin_amdgcn_exp2f(s);  // scores O(1): no max-sub
      lsum += p;
      // p-share: 1 write + 2 broadcast b128 reads (same-wave in-order LDS)
      pbuf[tid] = p;
      const float4 pq0 = *(const float4*)&pbuf[pbase];
      const float4 pq1 = *(const float4*)&pbuf[pbase + 4];
      const float* vr = vb + (size_t)k * 64 + r8 * 8;
      const float4 va = *(const float4*)(vr);
      const float4 vb4 = *(const float4*)(vr + 4);
      const float pm[8] = {pq0.x, pq0.y, pq0.z, pq0.w,
                           pq1.x, pq1.y, pq1.z, pq1.w};
#pragma unroll
      for (int m = 0; m < 8; ++m) {
        acc[m][0] += pm[m] * va.x;  acc[m][1] += pm[m] * va.y;
        acc[m][2] += pm[m] * va.z;  acc[m][3] += pm[m] * va.w;
        acc[m][4] += pm[m] * vb4.x; acc[m][5] += pm[m] * vb4.y;
        acc[m][6] += pm[m] * vb4.z; acc[m][7] += pm[m] * vb4.w;
      }
    }
  }

  // cross-wave combine: 4 partials per (row, dim); lsum totals once.
  const int lb = lane & ~7;
  lbuf[wave][lane] = lsum;
  float lt = 0.f;
  float* ob = att + (size_t)rowbase * 64 + r8 * 8;
#pragma unroll
  for (int mm = 0; mm < 8; mm += 2) {
    *(float4*)&cbuf[wave][lane][0] =
        make_float4(acc[mm][0], acc[mm][1], acc[mm][2], acc[mm][3]);
    *(float4*)&cbuf[wave][lane][4] =
        make_float4(acc[mm][4], acc[mm][5], acc[mm][6], acc[mm][7]);
    *(float4*)&cbuf[wave][lane][8] =
        make_float4(acc[mm + 1][0], acc[mm + 1][1], acc[mm + 1][2],
                    acc[mm + 1][3]);
    *(float4*)&cbuf[wave][lane][12] =
        make_float4(acc[mm + 1][4], acc[mm + 1][5], acc[mm + 1][6],
                    acc[mm + 1][7]);
    __syncthreads();
    if (mm == 0)
      lt = lbuf[0][lane] + lbuf[1][lane] + lbuf[2][lane] + lbuf[3][lane];
    if (wave == 0) {
      float s[16];
#pragma unroll
      for (int d4 = 0; d4 < 4; ++d4) {
        const float4 c0 = *(const float4*)&cbuf[0][lane][d4 * 4];
        const float4 c1 = *(const float4*)&cbuf[1][lane][d4 * 4];
        const float4 c2 = *(const float4*)&cbuf[2][lane][d4 * 4];
        const float4 c3 = *(const float4*)&cbuf[3][lane][d4 * 4];
        s[d4 * 4 + 0] = c0.x + c1.x + c2.x + c3.x;
        s[d4 * 4 + 1] = c0.y + c1.y + c2.y + c3.y;
        s[d4 * 4 + 2] = c0.z + c1.z + c2.z + c3.z;
        s[d4 * 4 + 3] = c0.w + c1.w + c2.w + c3.w;
      }
      const float im0 = 1.0f / bperm(lb + mm, lt);
      const float im1 = 1.0f / bperm(lb + mm + 1, lt);
      *(float4*)(ob + mm * 64) =
          make_float4(s[0] * im0, s[1] * im0, s[2] * im0, s[3] * im0);
      *(float4*)(ob + mm * 64 + 4) =
          make_float4(s[4] * im0, s[5] * im0, s[6] * im0, s[7] * im0);
      *(float4*)(ob + (mm + 1) * 64) =
          make_float4(s[8] * im1, s[9] * im1, s[10] * im1, s[11] * im1);
      *(float4*)(ob + (mm + 1) * 64 + 4) =
          make_float4(s[12] * im1, s[13] * im1, s[14] * im1, s[15] * im1);
    }
    __syncthreads();
  }
}

// Per-row MLP on folded weights, DS-lean (r15-proven).
__global__ __launch_bounds__(256) void mlp_kernel(
    const float* __restrict__ att,
    const float* __restrict__ w1p, const float* __restrict__ b1p,
    const float* __restrict__ W2, const float* __restrict__ b2,
    float* __restrict__ out) {
  __shared__ __align__(16) float w1s[NHID * 64];   // 12.8 KB
  __shared__ __align__(16) float w2s[NO * 52];     // 8.5 KB, 52-padded rows
  __shared__ float b1s[NHID], b2s[NO];
  const int tid = threadIdx.x;
  for (int i = tid; i < NHID * 64; i += 256) w1s[i] = w1p[i];
  for (int i = tid; i < NO * 52; i += 256) {
    const int oo = i / 52, o = i - oo * 52;
    w2s[i] = (o < NHID) ? W2[oo * NHID + o] : 0.f;
  }
  if (tid < NHID) b1s[tid] = b1p[tid];
  if (tid < NO) b2s[tid] = b2[tid];
  __syncthreads();

  const int row = blockIdx.x * 256 + tid;
  float ar[64];
  const float4* a4 = (const float4*)(att + (size_t)row * 64);
#pragma unroll
  for (int d4 = 0; d4 < 16; ++d4) {
    float4 v = a4[d4];
    ar[d4 * 4 + 0] = v.x;
    ar[d4 * 4 + 1] = v.y;
    ar[d4 * 4 + 2] = v.z;
    ar[d4 * 4 + 3] = v.w;
  }
  float h[52];
#pragma unroll 2
  for (int o = 0; o < NHID; ++o) {
    float acc = b1s[o];
    const float4* w4 = (const float4*)&w1s[o * 64];
#pragma unroll
    for (int i4 = 0; i4 < 16; ++i4) {
      float4 ww = w4[i4];
      acc += ar[i4 * 4 + 0] * ww.x + ar[i4 * 4 + 1] * ww.y +
             ar[i4 * 4 + 2] * ww.z + ar[i4 * 4 + 3] * ww.w;
    }
    h[o] = fmaxf(acc, 0.f);
  }
  h[50] = 0.f;
  h[51] = 0.f;
  float* orow = out + (size_t)row * NO;
#pragma unroll 2
  for (int oo = 0; oo < NO; ++oo) {
    float acc = b2s[oo];
    const float4* w4 = (const float4*)&w2s[oo * 52];
#pragma unroll
    for (int i4 = 0; i4 < 13; ++i4) {
      float4 ww = w4[i4];
      acc += h[i4 * 4 + 0] * ww.x + h[i4 * 4 + 1] * ww.y +
             h[i4 * 4 + 2] * ww.z + h[i4 * 4 + 3] * ww.w;
    }
    orow[oo] = acc;
  }
}

extern "C" void kernel_launch(void* const* d_in, const int* in_sizes, int n_in,
                              void* d_out, int out_size, void* d_ws, size_t ws_size,
                              hipStream_t stream) {
  const float* z = (const float*)d_in[0];
  const float* ts = (const float*)d_in[1];
  const float* refq = (const float*)d_in[2];
  const float* Wih_f = (const float*)d_in[3];
  const float* Whh_f = (const float*)d_in[4];
  const float* bih_f = (const float*)d_in[5];
  const float* bhh_f = (const float*)d_in[6];
  const float* Wih_b = (const float*)d_in[7];
  const float* Whh_b = (const float*)d_in[8];
  const float* bih_b = (const float*)d_in[9];
  const float* bhh_b = (const float*)d_in[10];
  const float* Wq = (const float*)d_in[11];
  const float* bq = (const float*)d_in[12];
  const float* Wk = (const float*)d_in[13];
  const float* bk = (const float*)d_in[14];
  const float* Wv = (const float*)d_in[15];
  const float* bv = (const float*)d_in[16];
  const float* W1 = (const float*)d_in[17];
  const float* b1 = (const float*)d_in[18];
  const float* W2 = (const float*)d_in[19];
  const float* b2 = (const float*)d_in[20];

  float* ws = (float*)d_ws;
  float* gi = ws;               // 3,145,728 (overlaid with att)
  float* att = ws;              // 4,194,304
  float* val = ws + 4194304;    // 1,048,576
  float* ktab = ws + 5242880;   // 8,192
  float* w1p = ws + 5251072;    // 3,200
  float* b1p = ws + 5254272;    // 64
  float* out = (float*)d_out;

  prep_all_kernel<<<131, 256, 0, stream>>>(
      refq, Wk, bk, Wv, bv, W1, b1, z, Wih_f, bih_f, bhh_f, Wih_b, bih_b,
      bhh_b, ktab, w1p, b1p, gi);
  gru_kernel<<<32, 64, 0, stream>>>(gi, Whh_f, bhh_f, Whh_b, bhh_b, val);
  attn_core_kernel<<<1024, 256, 0, stream>>>(ts, ktab, val, Wq, bq, att);
  mlp_kernel<<<256, 256, 0, stream>>>(att, w1p, b1p, W2, b2, out);
}

// Round 20
// 318.164 us; speedup vs baseline: 1.3134x; 1.0132x over previous
//
#include <hip/hip_runtime.h>
#include <hip/hip_bf16.h>
#include <math.h>

#define NB 32
#define NQ 2048
#define NK 512
#define NE 16
#define NH 32
#define NL 20
#define NHID 50
#define NO 41

#define LOG2E 1.4426950408889634f
#define TWO_LOG2E 2.8853900817779268f

// ws layout (floats):
// gi   : [64][512][96] @ 0        (3,145,728)  OVERLAID with att (gru before attn)
// att  : [65536][64]   @ 0        (4,194,304)  normalized P@val (pre-Wv)
// val  : [32][512][64] @ 4194304  (1,048,576)
// ktab : [512][16]     @ 5242880  (8,192)
// w1p  : [50][64]      @ 5251072  (3,200)      W1 @ Wv
// b1p  : [50]          @ 5254272  (64)         b1 + W1 @ bv
// total ~21.0 MB (proven size)

typedef __attribute__((ext_vector_type(2))) float f32x2;

__device__ __forceinline__ float bperm(int lane, float v) {
  return __builtin_bit_cast(
      float, __builtin_amdgcn_ds_bpermute(lane << 2, __builtin_bit_cast(int, v)));
}

// Merged prep (r18-proven): blocks 0-1 k-table; block 2 fold Wv into W1;
// blocks 3-130 input-side GRU gates (pre-scaled for exp2 activations).
__global__ __launch_bounds__(256) void prep_all_kernel(
    const float* __restrict__ refq, const float* __restrict__ Wk,
    const float* __restrict__ bk,
    const float* __restrict__ Wv, const float* __restrict__ bv,
    const float* __restrict__ W1, const float* __restrict__ b1,
    const float* __restrict__ z,
    const float* __restrict__ Wih_f, const float* __restrict__ bih_f,
    const float* __restrict__ bhh_f,
    const float* __restrict__ Wih_b, const float* __restrict__ bih_b,
    const float* __restrict__ bhh_b,
    float* __restrict__ ktab, float* __restrict__ w1p,
    float* __restrict__ b1p, float* __restrict__ gi) {
  const int tid = threadIdx.x;
  const int bid = blockIdx.x;
  if (bid < 2) {
    const int r = bid * 256 + tid;
    const float divs[8] = {1.0f, 0.74989421f, 0.56234133f, 0.42169650f,
                           0.31622777f, 0.23713737f, 0.17782794f, 0.13335214f};
    float pos = refq[r];
    float emb[NE];
#pragma unroll
    for (int m = 0; m < 8; ++m) {
      float a = 48.0f * pos * divs[m];
      emb[2 * m] = sinf(a);
      emb[2 * m + 1] = cosf(a);
    }
#pragma unroll
    for (int e = 0; e < NE; ++e) {
      float acc = bk[e];
#pragma unroll
      for (int i = 0; i < NE; ++i) acc += emb[i] * Wk[e * NE + i];
      ktab[r * NE + e] = acc;
    }
  } else if (bid == 2) {
    for (int e = tid; e < NHID * 64; e += 256) {
      const int o = e >> 6, i = e & 63;
      float acc = 0.f;
#pragma unroll 4
      for (int d = 0; d < 64; ++d) acc += W1[o * 64 + d] * Wv[d * 64 + i];
      w1p[e] = acc;
    }
    if (tid < NHID) {
      float acc = b1[tid];
#pragma unroll 4
      for (int d = 0; d < 64; ++d) acc += W1[tid * 64 + d] * bv[d];
      b1p[tid] = acc;
    }
  } else {
    const int row = (bid - 3) * 256 + tid;  // chain*512 + t
    const int c = row >> 9, t = row & 511;
    const int dir = c >> 5, b = c & 31;
    const float* __restrict__ Wih = dir ? Wih_b : Wih_f;
    const float* __restrict__ bih = dir ? bih_b : bih_f;
    const float* __restrict__ bhh = dir ? bhh_b : bhh_f;
    const float* __restrict__ zr = z + ((size_t)b * NK + t) * NL;
    float x[NL];
#pragma unroll
    for (int i = 0; i < NL; ++i) x[i] = zr[i];
    float* __restrict__ go = gi + (size_t)row * 96;
    for (int g = 0; g < 96; ++g) {
      float acc = bih[g] + (g < 64 ? bhh[g] : 0.f);
#pragma unroll
      for (int i = 0; i < NL; ++i) acc += x[i] * Wih[g * NL + i];
      go[g] = acc * (g < 64 ? LOG2E : TWO_LOG2E);
    }
  }
}

// Serial GRU (round-13, PASSED at 134 us): 2 chains per wave, full 32-dots,
// ONE DS round per step, exp2-folded activations, pk-FMA, pointer-walked IO.
__global__ __launch_bounds__(64) void gru_kernel(
    const float* __restrict__ gi,
    const float* __restrict__ Whh_f, const float* __restrict__ bhh_f,
    const float* __restrict__ Whh_b, const float* __restrict__ bhh_b,
    float* __restrict__ val) {
  __shared__ __align__(16) float hbuf[64];  // [chain-half][32]
  const int l = threadIdx.x;
  const int j = l & 31, half = l >> 5;
  const int c = blockIdx.x * 2 + half;   // 2|32 => both halves same dir
  const int dir = c >> 5, b = c & 31;
  const int hb = half * 32;
  const float* __restrict__ Whh = dir ? Whh_b : Whh_f;
  const float* __restrict__ bhh = dir ? bhh_b : bhh_f;

  // weights pre-scaled: r,z x log2e; n x 2*log2e (gi scaled to match)
  f32x2 wr[16], wz[16], wn[16];
#pragma unroll
  for (int i = 0; i < 16; ++i) {
    wr[i] = f32x2{Whh[j * 32 + 2 * i], Whh[j * 32 + 2 * i + 1]} * LOG2E;
    wz[i] = f32x2{Whh[(j + 32) * 32 + 2 * i], Whh[(j + 32) * 32 + 2 * i + 1]} *
            LOG2E;
    wn[i] = f32x2{Whh[(j + 64) * 32 + 2 * i], Whh[(j + 64) * 32 + 2 * i + 1]} *
            TWO_LOG2E;
  }
  const float bhn = bhh[j + 64] * TWO_LOG2E;
  float h = 0.f;
  hbuf[l] = 0.f;

  const float* __restrict__ gic = gi + (size_t)c * NK * 96;
  const int gstart = dir ? (NK - 1) * 96 : 0;
  const int gstride = dir ? -96 : 96;
  float* __restrict__ vp =
      val + ((size_t)b * NK + (dir ? NK - 1 : 0)) * 64 + dir * 32 + j;
  const int vstride = dir ? -64 : 64;

  float r0, z0, n0, r1, z1, n1, r2, z2, n2, r3, z3, n3;
  int gidx = gstart;
  auto giload = [&](float& gr, float& gz, float& gn) {
    const float* p = gic + gidx;
    gr = p[j];
    gz = p[32 + j];
    gn = p[64 + j];
    gidx += gstride;
  };
  giload(r0, z0, n0);
  giload(r1, z1, n1);
  giload(r2, z2, n2);
  giload(r3, z3, n3);

  auto step = [&](bool pf, float& gr, float& gz, float& gn) {
    const float gir = gr, giz = gz, gin = gn;
    if (pf) giload(gr, gz, gn);  // global prefetch (vmcnt queue)
    hbuf[l] = h;  // same-wave LDS is in-order (proven rounds 4-19)
    f32x2 hv[16];
#pragma unroll
    for (int t = 0; t < 4; ++t) {
      const float4 hq = *(const float4*)&hbuf[hb + t * 8];
      const float4 hq2 = *(const float4*)&hbuf[hb + t * 8 + 4];
      hv[t * 4 + 0] = f32x2{hq.x, hq.y};
      hv[t * 4 + 1] = f32x2{hq.z, hq.w};
      hv[t * 4 + 2] = f32x2{hq2.x, hq2.y};
      hv[t * 4 + 3] = f32x2{hq2.z, hq2.w};
    }
    f32x2 sr2 = {0.f, 0.f}, sz2 = {0.f, 0.f}, sn2 = {0.f, 0.f};
    f32x2 sr3 = {0.f, 0.f}, sz3 = {0.f, 0.f}, sn3 = {0.f, 0.f};
#pragma unroll
    for (int t = 0; t < 8; ++t) {
      sr2 = __builtin_elementwise_fma(wr[t], hv[t], sr2);
      sz2 = __builtin_elementwise_fma(wz[t], hv[t], sz2);
      sn2 = __builtin_elementwise_fma(wn[t], hv[t], sn2);
      sr3 = __builtin_elementwise_fma(wr[8 + t], hv[8 + t], sr3);
      sz3 = __builtin_elementwise_fma(wz[8 + t], hv[8 + t], sz3);
      sn3 = __builtin_elementwise_fma(wn[8 + t], hv[8 + t], sn3);
    }
    const float sr = (sr2.x + sr2.y) + (sr3.x + sr3.y);
    const float sz = (sz2.x + sz2.y) + (sz3.x + sz3.y);
    const float sn = (sn2.x + sn2.y) + (sn3.x + sn3.y);
    const float rg =
        __builtin_amdgcn_rcpf(1.0f + __builtin_amdgcn_exp2f(-(gir + sr)));
    const float ug =
        __builtin_amdgcn_rcpf(1.0f + __builtin_amdgcn_exp2f(-(giz + sz)));
    const float ng =
        1.0f - 2.0f * __builtin_amdgcn_rcpf(
                          __builtin_amdgcn_exp2f(gin + rg * (sn + bhn)) + 1.0f);
    h = ng + ug * (h - ng);
    *vp = h;
    vp += vstride;
  };
  for (int s = 0; s < NK; s += 4) {
    step(s + 4 < NK, r0, z0, n0);
    step(s + 5 < NK, r1, z1, n1);
    step(s + 6 < NK, r2, z2, n2);
    step(s + 7 < NK, r3, z3, n3);
  }
}

// R=8 attention v8 = r15-v4 + kt staged in LDS (skewed, conflict-free) with
// a slimmed combine buffer so LDS stays <= 40KB -> 4 blocks/CU preserved.
// Mechanism: kt global loads were 4 of 6 VMEM instr/iter -> VMEM-issue port
// saturation (why r16's extra waves didn't help). Now 2 VMEM + 7 DS per iter.
__global__ __launch_bounds__(256) void attn_core_kernel(
    const float* __restrict__ tsteps, const float* __restrict__ ktab,
    const float* __restrict__ val,
    const float* __restrict__ Wq, const float* __restrict__ bq,
    float* __restrict__ att) {
  __shared__ __align__(16) float kts[8220];          // 32.9 KB skewed k-table
  __shared__ __align__(16) float cbuf[4][64][4];     // 4 KB combine buffer
  __shared__ __align__(16) float pbuf[256];          // 1 KB p-share
  __shared__ float lbuf[4][64];                      // 1 KB lsum partials
  __shared__ float wqs[NE * NE];
  __shared__ float bqs[NE];
  const int tid = threadIdx.x;
  for (int i = tid; i < NK * NE; i += 256) {
    const int k = i >> 4, e = i & 15;
    kts[(k << 4) + (((k >> 3) & 7) << 2) + e] = ktab[i];
  }
  for (int i = tid; i < NE * NE; i += 256) wqs[i] = Wq[i];
  if (tid < NE) bqs[tid] = bq[tid];
  __syncthreads();

  const int lane = tid & 63;
  const int g = lane >> 3;      // group 0..7
  const int r8 = lane & 7;      // row-in-group for scoring; d-eighth for acc
  const int wave = tid >> 6;    // k-quarter owner
  const int rowbase = blockIdx.x * 64 + g * 8;
  const int myrow = rowbase + r8;
  const int b = myrow >> 11;    // uniform per block (64-row span, 64|2048)

  const float pos = tsteps[myrow];
  const float divs[8] = {1.0f, 0.74989421f, 0.56234133f, 0.42169650f,
                         0.31622777f, 0.23713737f, 0.17782794f, 0.13335214f};
  float emb[NE];
#pragma unroll
  for (int m = 0; m < 8; ++m) {
    float a = 48.0f * pos * divs[m];
    emb[2 * m] = sinf(a);
    emb[2 * m + 1] = cosf(a);
  }
  float q[NE];
#pragma unroll
  for (int e = 0; e < NE; ++e) {
    float acc = bqs[e];
#pragma unroll
    for (int i = 0; i < NE; ++i) acc += emb[i] * wqs[e * NE + i];
    q[e] = acc * (0.25f * LOG2E);  // fold 1/sqrt(E) and log2e (exp2 direct)
  }
  const int pbase = tid & ~7;  // this wave's group slot in pbuf
  const float* __restrict__ vb = val + (size_t)b * NK * 64;

  float acc[8][8];
#pragma unroll
  for (int m = 0; m < 8; ++m)
#pragma unroll
    for (int d = 0; d < 8; ++d) acc[m][d] = 0.f;
  float lsum = 0.f;

#pragma unroll
  for (int kb = 0; kb < 2; ++kb) {
    const int khi = (wave << 1) | kb;   // this wave's k-block (uniform)
#pragma unroll 2
    for (int i = 0; i < 64; ++i) {
      const int ii = (i + g * 8) & 63;  // group stagger: distinct rows/instr
      const int k = (khi << 6) | ii;
      const float4* kr =
          (const float4*)&kts[(k << 4) + (((k >> 3) & 7) << 2)];  // LDS, skewed
      const float4 k0 = kr[0], k1 = kr[1], k2 = kr[2], k3 = kr[3];
      float s;
      s  = q[0] * k0.x + q[1] * k0.y + q[2] * k0.z + q[3] * k0.w;
      s += q[4] * k1.x + q[5] * k1.y + q[6] * k1.z + q[7] * k1.w;
      s += q[8] * k2.x + q[9] * k2.y + q[10] * k2.z + q[11] * k2.w;
      s += q[12] * k3.x + q[13] * k3.y + q[14] * k3.z + q[15] * k3.w;
      const float p = __builtin_amdgcn_exp2f(s);  // scores O(1): no max-sub
      lsum += p;
      // p-share: 1 write + 2 broadcast b128 reads (same-wave in-order LDS)
      pbuf[tid] = p;
      const float4 pq0 = *(const float4*)&pbuf[pbase];
      const float4 pq1 = *(const float4*)&pbuf[pbase + 4];
      const float* vr = vb + (size_t)k * 64 + r8 * 8;
      const float4 va = *(const float4*)(vr);
      const float4 vb4 = *(const float4*)(vr + 4);
      const float pm[8] = {pq0.x, pq0.y, pq0.z, pq0.w,
                           pq1.x, pq1.y, pq1.z, pq1.w};
#pragma unroll
      for (int m = 0; m < 8; ++m) {
        acc[m][0] += pm[m] * va.x;  acc[m][1] += pm[m] * va.y;
        acc[m][2] += pm[m] * va.z;  acc[m][3] += pm[m] * va.w;
        acc[m][4] += pm[m] * vb4.x; acc[m][5] += pm[m] * vb4.y;
        acc[m][6] += pm[m] * vb4.z; acc[m][7] += pm[m] * vb4.w;
      }
    }
  }

  // cross-wave combine: 4 partials per (row, half-row); 16 slim rounds.
  const int lb = lane & ~7;
  lbuf[wave][lane] = lsum;
  float lt = 0.f;
  float* ob = att + (size_t)rowbase * 64 + r8 * 8;
#pragma unroll
  for (int rr = 0; rr < 16; ++rr) {
    const int mm = rr >> 1, hf = rr & 1;
    *(float4*)&cbuf[wave][lane][0] =
        make_float4(acc[mm][hf * 4 + 0], acc[mm][hf * 4 + 1],
                    acc[mm][hf * 4 + 2], acc[mm][hf * 4 + 3]);
    __syncthreads();
    if (rr == 0)
      lt = lbuf[0][lane] + lbuf[1][lane] + lbuf[2][lane] + lbuf[3][lane];
    if (wave == 0) {
      const float4 c0 = *(const float4*)&cbuf[0][lane][0];
      const float4 c1 = *(const float4*)&cbuf[1][lane][0];
      const float4 c2 = *(const float4*)&cbuf[2][lane][0];
      const float4 c3 = *(const float4*)&cbuf[3][lane][0];
      const float im = 1.0f / bperm(lb + mm, lt);
      *(float4*)(ob + mm * 64 + hf * 4) = make_float4(
          (c0.x + c1.x + c2.x + c3.x) * im, (c0.y + c1.y + c2.y + c3.y) * im,
          (c0.z + c1.z + c2.z + c3.z) * im, (c0.w + c1.w + c2.w + c3.w) * im);
    }
    __syncthreads();
  }
}

// Per-row MLP on folded weights, DS-lean (r15-proven).
__global__ __launch_bounds__(256) void mlp_kernel(
    const float* __restrict__ att,
    const float* __restrict__ w1p, const float* __restrict__ b1p,
    const float* __restrict__ W2, const float* __restrict__ b2,
    float* __restrict__ out) {
  __shared__ __align__(16) float w1s[NHID * 64];   // 12.8 KB
  __shared__ __align__(16) float w2s[NO * 52];     // 8.5 KB, 52-padded rows
  __shared__ float b1s[NHID], b2s[NO];
  const int tid = threadIdx.x;
  for (int i = tid; i < NHID * 64; i += 256) w1s[i] = w1p[i];
  for (int i = tid; i < NO * 52; i += 256) {
    const int oo = i / 52, o = i - oo * 52;
    w2s[i] = (o < NHID) ? W2[oo * NHID + o] : 0.f;
  }
  if (tid < NHID) b1s[tid] = b1p[tid];
  if (tid < NO) b2s[tid] = b2[tid];
  __syncthreads();

  const int row = blockIdx.x * 256 + tid;
  float ar[64];
  const float4* a4 = (const float4*)(att + (size_t)row * 64);
#pragma unroll
  for (int d4 = 0; d4 < 16; ++d4) {
    float4 v = a4[d4];
    ar[d4 * 4 + 0] = v.x;
    ar[d4 * 4 + 1] = v.y;
    ar[d4 * 4 + 2] = v.z;
    ar[d4 * 4 + 3] = v.w;
  }
  float h[52];
#pragma unroll 2
  for (int o = 0; o < NHID; ++o) {
    float acc = b1s[o];
    const float4* w4 = (const float4*)&w1s[o * 64];
#pragma unroll
    for (int i4 = 0; i4 < 16; ++i4) {
      float4 ww = w4[i4];
      acc += ar[i4 * 4 + 0] * ww.x + ar[i4 * 4 + 1] * ww.y +
             ar[i4 * 4 + 2] * ww.z + ar[i4 * 4 + 3] * ww.w;
    }
    h[o] = fmaxf(acc, 0.f);
  }
  h[50] = 0.f;
  h[51] = 0.f;
  float* orow = out + (size_t)row * NO;
#pragma unroll 2
  for (int oo = 0; oo < NO; ++oo) {
    float acc = b2s[oo];
    const float4* w4 = (const float4*)&w2s[oo * 52];
#pragma unroll
    for (int i4 = 0; i4 < 13; ++i4) {
      float4 ww = w4[i4];
      acc += h[i4 * 4 + 0] * ww.x + h[i4 * 4 + 1] * ww.y +
             h[i4 * 4 + 2] * ww.z + h[i4 * 4 + 3] * ww.w;
    }
    orow[oo] = acc;
  }
}

extern "C" void kernel_launch(void* const* d_in, const int* in_sizes, int n_in,
                              void* d_out, int out_size, void* d_ws, size_t ws_size,
                              hipStream_t stream) {
  const float* z = (const float*)d_in[0];
  const float* ts = (const float*)d_in[1];
  const float* refq = (const float*)d_in[2];
  const float* Wih_f = (const float*)d_in[3];
  const float* Whh_f = (const float*)d_in[4];
  const float* bih_f = (const float*)d_in[5];
  const float* bhh_f = (const float*)d_in[6];
  const float* Wih_b = (const float*)d_in[7];
  const float* Whh_b = (const float*)d_in[8];
  const float* bih_b = (const float*)d_in[9];
  const float* bhh_b = (const float*)d_in[10];
  const float* Wq = (const float*)d_in[11];
  const float* bq = (const float*)d_in[12];
  const float* Wk = (const float*)d_in[13];
  const float* bk = (const float*)d_in[14];
  const float* Wv = (const float*)d_in[15];
  const float* bv = (const float*)d_in[16];
  const float* W1 = (const float*)d_in[17];
  const float* b1 = (const float*)d_in[18];
  const float* W2 = (const float*)d_in[19];
  const float* b2 = (const float*)d_in[20];

  float* ws = (float*)d_ws;
  float* gi = ws;               // 3,145,728 (overlaid with att)
  float* att = ws;              // 4,194,304
  float* val = ws + 4194304;    // 1,048,576
  float* ktab = ws + 5242880;   // 8,192
  float* w1p = ws + 5251072;    // 3,200
  float* b1p = ws + 5254272;    // 64
  float* out = (float*)d_out;

  prep_all_kernel<<<131, 256, 0, stream>>>(
      refq, Wk, bk, Wv, bv, W1, b1, z, Wih_f, bih_f, bhh_f, Wih_b, bih_b,
      bhh_b, ktab, w1p, b1p, gi);
  gru_kernel<<<32, 64, 0, stream>>>(gi, Whh_f, bhh_f, Whh_b, bhh_b, val);
  attn_core_kernel<<<1024, 256, 0, stream>>>(ts, ktab, val, Wq, bq, att);
  mlp_kernel<<<256, 256, 0, stream>>>(att, w1p, b1p, W2, b2, out);
}

// Round 21
// 300.515 us; speedup vs baseline: 1.3905x; 1.0587x over previous
//
#include <hip/hip_runtime.h>
#include <hip/hip_bf16.h>
#include <math.h>

#define NB 32
#define NQ 2048
#define NK 512
#define NE 16
#define NH 32
#define NL 20
#define NHID 50
#define NO 41

#define LOG2E 1.4426950408889634f
#define TWO_LOG2E 2.8853900817779268f

// ws layout (floats):
// gi   : [64][512][96] @ 0        (3,145,728)  OVERLAID with att (gru before attn)
// att  : [65536][64]   @ 0        (4,194,304)  normalized P@val (pre-Wv)
// val  : [32][512][64] @ 4194304  (1,048,576)
// ktab : [512][16]     @ 5242880  (8,192)
// w1p  : [50][64]      @ 5251072  (3,200)      W1 @ Wv
// b1p  : [50]          @ 5254272  (64)         b1 + W1 @ bv
// total ~21.0 MB (proven size)

typedef __attribute__((ext_vector_type(2))) float f32x2;

__device__ __forceinline__ float bperm(int lane, float v) {
  return __builtin_bit_cast(
      float, __builtin_amdgcn_ds_bpermute(lane << 2, __builtin_bit_cast(int, v)));
}

// Merged prep (r18-proven): blocks 0-1 k-table; block 2 fold Wv into W1;
// blocks 3-130 input-side GRU gates (pre-scaled, float4 stores).
__global__ __launch_bounds__(256) void prep_all_kernel(
    const float* __restrict__ refq, const float* __restrict__ Wk,
    const float* __restrict__ bk,
    const float* __restrict__ Wv, const float* __restrict__ bv,
    const float* __restrict__ W1, const float* __restrict__ b1,
    const float* __restrict__ z,
    const float* __restrict__ Wih_f, const float* __restrict__ bih_f,
    const float* __restrict__ bhh_f,
    const float* __restrict__ Wih_b, const float* __restrict__ bih_b,
    const float* __restrict__ bhh_b,
    float* __restrict__ ktab, float* __restrict__ w1p,
    float* __restrict__ b1p, float* __restrict__ gi) {
  const int tid = threadIdx.x;
  const int bid = blockIdx.x;
  if (bid < 2) {
    const int r = bid * 256 + tid;
    const float divs[8] = {1.0f, 0.74989421f, 0.56234133f, 0.42169650f,
                           0.31622777f, 0.23713737f, 0.17782794f, 0.13335214f};
    float pos = refq[r];
    float emb[NE];
#pragma unroll
    for (int m = 0; m < 8; ++m) {
      float a = 48.0f * pos * divs[m];
      emb[2 * m] = sinf(a);
      emb[2 * m + 1] = cosf(a);
    }
#pragma unroll
    for (int e = 0; e < NE; ++e) {
      float acc = bk[e];
#pragma unroll
      for (int i = 0; i < NE; ++i) acc += emb[i] * Wk[e * NE + i];
      ktab[r * NE + e] = acc;
    }
  } else if (bid == 2) {
    for (int e = tid; e < NHID * 64; e += 256) {
      const int o = e >> 6, i = e & 63;
      float acc = 0.f;
#pragma unroll 4
      for (int d = 0; d < 64; ++d) acc += W1[o * 64 + d] * Wv[d * 64 + i];
      w1p[e] = acc;
    }
    if (tid < NHID) {
      float acc = b1[tid];
#pragma unroll 4
      for (int d = 0; d < 64; ++d) acc += W1[tid * 64 + d] * bv[d];
      b1p[tid] = acc;
    }
  } else {
    const int row = (bid - 3) * 256 + tid;  // chain*512 + t
    const int c = row >> 9, t = row & 511;
    const int dir = c >> 5, b = c & 31;
    const float* __restrict__ Wih = dir ? Wih_b : Wih_f;
    const float* __restrict__ bih = dir ? bih_b : bih_f;
    const float* __restrict__ bhh = dir ? bhh_b : bhh_f;
    const float* __restrict__ zr = z + ((size_t)b * NK + t) * NL;
    float x[NL];
#pragma unroll
    for (int i = 0; i < NL; ++i) x[i] = zr[i];
    float4* __restrict__ go4 = (float4*)(gi + (size_t)row * 96);
#pragma unroll 2
    for (int g4 = 0; g4 < 24; ++g4) {
      float o[4];
#pragma unroll
      for (int u = 0; u < 4; ++u) {
        const int g = g4 * 4 + u;
        float acc = bih[g] + (g < 64 ? bhh[g] : 0.f);
#pragma unroll
        for (int i = 0; i < NL; ++i) acc += x[i] * Wih[g * NL + i];
        o[u] = acc * (g < 64 ? LOG2E : TWO_LOG2E);
      }
      go4[g4] = make_float4(o[0], o[1], o[2], o[3]);
    }
  }
}

// Serial GRU v5 = r13 structure + register-pipelined h-broadcast: the
// hbuf write + 8 b128 reads for step s+1 issue at the END of step s
// (right after h is computed), so val-store/gi-prefetch/loop overhead
// overlaps the DS round instead of preceding it.
__global__ __launch_bounds__(64) void gru_kernel(
    const float* __restrict__ gi,
    const float* __restrict__ Whh_f, const float* __restrict__ bhh_f,
    const float* __restrict__ Whh_b, const float* __restrict__ bhh_b,
    float* __restrict__ val) {
  __shared__ __align__(16) float hbuf[64];  // [chain-half][32]
  const int l = threadIdx.x;
  const int j = l & 31, half = l >> 5;
  const int c = blockIdx.x * 2 + half;   // 2|32 => both halves same dir
  const int dir = c >> 5, b = c & 31;
  const int hb = half * 32;
  const float* __restrict__ Whh = dir ? Whh_b : Whh_f;
  const float* __restrict__ bhh = dir ? bhh_b : bhh_f;

  // weights pre-scaled: r,z x log2e; n x 2*log2e (gi scaled to match)
  f32x2 wr[16], wz[16], wn[16];
#pragma unroll
  for (int i = 0; i < 16; ++i) {
    wr[i] = f32x2{Whh[j * 32 + 2 * i], Whh[j * 32 + 2 * i + 1]} * LOG2E;
    wz[i] = f32x2{Whh[(j + 32) * 32 + 2 * i], Whh[(j + 32) * 32 + 2 * i + 1]} *
            LOG2E;
    wn[i] = f32x2{Whh[(j + 64) * 32 + 2 * i], Whh[(j + 64) * 32 + 2 * i + 1]} *
            TWO_LOG2E;
  }
  const float bhn = bhh[j + 64] * TWO_LOG2E;
  float h = 0.f;
  hbuf[l] = 0.f;

  // pipelined h-broadcast registers; h0 = 0 => hv starts all-zero
  f32x2 hv[16];
#pragma unroll
  for (int t = 0; t < 16; ++t) hv[t] = f32x2{0.f, 0.f};

  const float* __restrict__ gic = gi + (size_t)c * NK * 96;
  const int gstart = dir ? (NK - 1) * 96 : 0;
  const int gstride = dir ? -96 : 96;
  float* __restrict__ vp =
      val + ((size_t)b * NK + (dir ? NK - 1 : 0)) * 64 + dir * 32 + j;
  const int vstride = dir ? -64 : 64;

  float r0, z0, n0, r1, z1, n1, r2, z2, n2, r3, z3, n3;
  int gidx = gstart;
  auto giload = [&](float& gr, float& gz, float& gn) {
    const float* p = gic + gidx;
    gr = p[j];
    gz = p[32 + j];
    gn = p[64 + j];
    gidx += gstride;
  };
  giload(r0, z0, n0);
  giload(r1, z1, n1);
  giload(r2, z2, n2);
  giload(r3, z3, n3);

  auto step = [&](bool pf, float& gr, float& gz, float& gn) {
    const float gir = gr, giz = gz, gin = gn;
    if (pf) giload(gr, gz, gn);  // global prefetch (vmcnt queue)
    // dots from PRE-LOADED hv (reads issued at end of previous step)
    f32x2 sr2 = {0.f, 0.f}, sz2 = {0.f, 0.f}, sn2 = {0.f, 0.f};
    f32x2 sr3 = {0.f, 0.f}, sz3 = {0.f, 0.f}, sn3 = {0.f, 0.f};
#pragma unroll
    for (int t = 0; t < 8; ++t) {
      sr2 = __builtin_elementwise_fma(wr[t], hv[t], sr2);
      sz2 = __builtin_elementwise_fma(wz[t], hv[t], sz2);
      sn2 = __builtin_elementwise_fma(wn[t], hv[t], sn2);
      sr3 = __builtin_elementwise_fma(wr[8 + t], hv[8 + t], sr3);
      sz3 = __builtin_elementwise_fma(wz[8 + t], hv[8 + t], sz3);
      sn3 = __builtin_elementwise_fma(wn[8 + t], hv[8 + t], sn3);
    }
    const float sr = (sr2.x + sr2.y) + (sr3.x + sr3.y);
    const float sz = (sz2.x + sz2.y) + (sz3.x + sz3.y);
    const float sn = (sn2.x + sn2.y) + (sn3.x + sn3.y);
    const float rg =
        __builtin_amdgcn_rcpf(1.0f + __builtin_amdgcn_exp2f(-(gir + sr)));
    const float ug =
        __builtin_amdgcn_rcpf(1.0f + __builtin_amdgcn_exp2f(-(giz + sz)));
    const float ng =
        1.0f - 2.0f * __builtin_amdgcn_rcpf(
                          __builtin_amdgcn_exp2f(gin + rg * (sn + bhn)) + 1.0f);
    h = ng + ug * (h - ng);
    // DS round for NEXT step issues immediately after h (same-wave in-order
    // LDS, proven r4-r20); val store + gi/loop overhead overlap its latency
    hbuf[l] = h;
#pragma unroll
    for (int t = 0; t < 4; ++t) {
      const float4 hq = *(const float4*)&hbuf[hb + t * 8];
      const float4 hq2 = *(const float4*)&hbuf[hb + t * 8 + 4];
      hv[t * 4 + 0] = f32x2{hq.x, hq.y};
      hv[t * 4 + 1] = f32x2{hq.z, hq.w};
      hv[t * 4 + 2] = f32x2{hq2.x, hq2.y};
      hv[t * 4 + 3] = f32x2{hq2.z, hq2.w};
    }
    *vp = h;
    vp += vstride;
  };
  for (int s = 0; s < NK; s += 4) {
    step(s + 4 < NK, r0, z0, n0);
    step(s + 5 < NK, r1, z1, n1);
    step(s + 6 < NK, r2, z2, n2);
    step(s + 7 < NK, r3, z3, n3);
  }
}

// R=8 attention v8 (r20-proven): kt in skewed LDS, slim combine, 4 blocks/CU.
__global__ __launch_bounds__(256) void attn_core_kernel(
    const float* __restrict__ tsteps, const float* __restrict__ ktab,
    const float* __restrict__ val,
    const float* __restrict__ Wq, const float* __restrict__ bq,
    float* __restrict__ att) {
  __shared__ __align__(16) float kts[8220];          // 32.9 KB skewed k-table
  __shared__ __align__(16) float cbuf[4][64][4];     // 4 KB combine buffer
  __shared__ __align__(16) float pbuf[256];          // 1 KB p-share
  __shared__ float lbuf[4][64];                      // 1 KB lsum partials
  __shared__ float wqs[NE * NE];
  __shared__ float bqs[NE];
  const int tid = threadIdx.x;
  for (int i = tid; i < NK * NE; i += 256) {
    const int k = i >> 4, e = i & 15;
    kts[(k << 4) + (((k >> 3) & 7) << 2) + e] = ktab[i];
  }
  for (int i = tid; i < NE * NE; i += 256) wqs[i] = Wq[i];
  if (tid < NE) bqs[tid] = bq[tid];
  __syncthreads();

  const int lane = tid & 63;
  const int g = lane >> 3;      // group 0..7
  const int r8 = lane & 7;      // row-in-group for scoring; d-eighth for acc
  const int wave = tid >> 6;    // k-quarter owner
  const int rowbase = blockIdx.x * 64 + g * 8;
  const int myrow = rowbase + r8;
  const int b = myrow >> 11;    // uniform per block (64-row span, 64|2048)

  const float pos = tsteps[myrow];
  const float divs[8] = {1.0f, 0.74989421f, 0.56234133f, 0.42169650f,
                         0.31622777f, 0.23713737f, 0.17782794f, 0.13335214f};
  float emb[NE];
#pragma unroll
  for (int m = 0; m < 8; ++m) {
    float a = 48.0f * pos * divs[m];
    emb[2 * m] = sinf(a);
    emb[2 * m + 1] = cosf(a);
  }
  float q[NE];
#pragma unroll
  for (int e = 0; e < NE; ++e) {
    float acc = bqs[e];
#pragma unroll
    for (int i = 0; i < NE; ++i) acc += emb[i] * wqs[e * NE + i];
    q[e] = acc * (0.25f * LOG2E);  // fold 1/sqrt(E) and log2e (exp2 direct)
  }
  const int pbase = tid & ~7;  // this wave's group slot in pbuf
  const float* __restrict__ vb = val + (size_t)b * NK * 64;

  float acc[8][8];
#pragma unroll
  for (int m = 0; m < 8; ++m)
#pragma unroll
    for (int d = 0; d < 8; ++d) acc[m][d] = 0.f;
  float lsum = 0.f;

#pragma unroll
  for (int kb = 0; kb < 2; ++kb) {
    const int khi = (wave << 1) | kb;   // this wave's k-block (uniform)
#pragma unroll 2
    for (int i = 0; i < 64; ++i) {
      const int ii = (i + g * 8) & 63;  // group stagger: distinct rows/instr
      const int k = (khi << 6) | ii;
      const float4* kr =
          (const float4*)&kts[(k << 4) + (((k >> 3) & 7) << 2)];  // LDS, skewed
      const float4 k0 = kr[0], k1 = kr[1], k2 = kr[2], k3 = kr[3];
      float s;
      s  = q[0] * k0.x + q[1] * k0.y + q[2] * k0.z + q[3] * k0.w;
      s += q[4] * k1.x + q[5] * k1.y + q[6] * k1.z + q[7] * k1.w;
      s += q[8] * k2.x + q[9] * k2.y + q[10] * k2.z + q[11] * k2.w;
      s += q[12] * k3.x + q[13] * k3.y + q[14] * k3.z + q[15] * k3.w;
      const float p = __builtin_amdgcn_exp2f(s);  // scores O(1): no max-sub
      lsum += p;
      // p-share: 1 write + 2 broadcast b128 reads (same-wave in-order LDS)
      pbuf[tid] = p;
      const float4 pq0 = *(const float4*)&pbuf[pbase];
      const float4 pq1 = *(const float4*)&pbuf[pbase + 4];
      const float* vr = vb + (size_t)k * 64 + r8 * 8;
      const float4 va = *(const float4*)(vr);
      const float4 vb4 = *(const float4*)(vr + 4);
      const float pm[8] = {pq0.x, pq0.y, pq0.z, pq0.w,
                           pq1.x, pq1.y, pq1.z, pq1.w};
#pragma unroll
      for (int m = 0; m < 8; ++m) {
        acc[m][0] += pm[m] * va.x;  acc[m][1] += pm[m] * va.y;
        acc[m][2] += pm[m] * va.z;  acc[m][3] += pm[m] * va.w;
        acc[m][4] += pm[m] * vb4.x; acc[m][5] += pm[m] * vb4.y;
        acc[m][6] += pm[m] * vb4.z; acc[m][7] += pm[m] * vb4.w;
      }
    }
  }

  // cross-wave combine: 4 partials per (row, half-row); 16 slim rounds.
  const int lb = lane & ~7;
  lbuf[wave][lane] = lsum;
  float lt = 0.f;
  float* ob = att + (size_t)rowbase * 64 + r8 * 8;
#pragma unroll
  for (int rr = 0; rr < 16; ++rr) {
    const int mm = rr >> 1, hf = rr & 1;
    *(float4*)&cbuf[wave][lane][0] =
        make_float4(acc[mm][hf * 4 + 0], acc[mm][hf * 4 + 1],
                    acc[mm][hf * 4 + 2], acc[mm][hf * 4 + 3]);
    __syncthreads();
    if (rr == 0)
      lt = lbuf[0][lane] + lbuf[1][lane] + lbuf[2][lane] + lbuf[3][lane];
    if (wave == 0) {
      const float4 c0 = *(const float4*)&cbuf[0][lane][0];
      const float4 c1 = *(const float4*)&cbuf[1][lane][0];
      const float4 c2 = *(const float4*)&cbuf[2][lane][0];
      const float4 c3 = *(const float4*)&cbuf[3][lane][0];
      const float im = 1.0f / bperm(lb + mm, lt);
      *(float4*)(ob + mm * 64 + hf * 4) = make_float4(
          (c0.x + c1.x + c2.x + c3.x) * im, (c0.y + c1.y + c2.y + c3.y) * im,
          (c0.z + c1.z + c2.z + c3.z) * im, (c0.w + c1.w + c2.w + c3.w) * im);
    }
    __syncthreads();
  }
}

// Per-row MLP on folded weights, DS-lean (r15-proven).
__global__ __launch_bounds__(256) void mlp_kernel(
    const float* __restrict__ att,
    const float* __restrict__ w1p, const float* __restrict__ b1p,
    const float* __restrict__ W2, const float* __restrict__ b2,
    float* __restrict__ out) {
  __shared__ __align__(16) float w1s[NHID * 64];   // 12.8 KB
  __shared__ __align__(16) float w2s[NO * 52];     // 8.5 KB, 52-padded rows
  __shared__ float b1s[NHID], b2s[NO];
  const int tid = threadIdx.x;
  for (int i = tid; i < NHID * 64; i += 256) w1s[i] = w1p[i];
  for (int i = tid; i < NO * 52; i += 256) {
    const int oo = i / 52, o = i - oo * 52;
    w2s[i] = (o < NHID) ? W2[oo * NHID + o] : 0.f;
  }
  if (tid < NHID) b1s[tid] = b1p[tid];
  if (tid < NO) b2s[tid] = b2[tid];
  __syncthreads();

  const int row = blockIdx.x * 256 + tid;
  float ar[64];
  const float4* a4 = (const float4*)(att + (size_t)row * 64);
#pragma unroll
  for (int d4 = 0; d4 < 16; ++d4) {
    float4 v = a4[d4];
    ar[d4 * 4 + 0] = v.x;
    ar[d4 * 4 + 1] = v.y;
    ar[d4 * 4 + 2] = v.z;
    ar[d4 * 4 + 3] = v.w;
  }
  float h[52];
#pragma unroll 2
  for (int o = 0; o < NHID; ++o) {
    float acc = b1s[o];
    const float4* w4 = (const float4*)&w1s[o * 64];
#pragma unroll
    for (int i4 = 0; i4 < 16; ++i4) {
      float4 ww = w4[i4];
      acc += ar[i4 * 4 + 0] * ww.x + ar[i4 * 4 + 1] * ww.y +
             ar[i4 * 4 + 2] * ww.z + ar[i4 * 4 + 3] * ww.w;
    }
    h[o] = fmaxf(acc, 0.f);
  }
  h[50] = 0.f;
  h[51] = 0.f;
  float* orow = out + (size_t)row * NO;
#pragma unroll 2
  for (int oo = 0; oo < NO; ++oo) {
    float acc = b2s[oo];
    const float4* w4 = (const float4*)&w2s[oo * 52];
#pragma unroll
    for (int i4 = 0; i4 < 13; ++i4) {
      float4 ww = w4[i4];
      acc += h[i4 * 4 + 0] * ww.x + h[i4 * 4 + 1] * ww.y +
             h[i4 * 4 + 2] * ww.z + h[i4 * 4 + 3] * ww.w;
    }
    orow[oo] = acc;
  }
}

extern "C" void kernel_launch(void* const* d_in, const int* in_sizes, int n_in,
                              void* d_out, int out_size, void* d_ws, size_t ws_size,
                              hipStream_t stream) {
  const float* z = (const float*)d_in[0];
  const float* ts = (const float*)d_in[1];
  const float* refq = (const float*)d_in[2];
  const float* Wih_f = (const float*)d_in[3];
  const float* Whh_f = (const float*)d_in[4];
  const float* bih_f = (const float*)d_in[5];
  const float* bhh_f = (const float*)d_in[6];
  const float* Wih_b = (const float*)d_in[7];
  const float* Whh_b = (const float*)d_in[8];
  const float* bih_b = (const float*)d_in[9];
  const float* bhh_b = (const float*)d_in[10];
  const float* Wq = (const float*)d_in[11];
  const float* bq = (const float*)d_in[12];
  const float* Wk = (const float*)d_in[13];
  const float* bk = (const float*)d_in[14];
  const float* Wv = (const float*)d_in[15];
  const float* bv = (const float*)d_in[16];
  const float* W1 = (const float*)d_in[17];
  const float* b1 = (const float*)d_in[18];
  const float* W2 = (const float*)d_in[19];
  const float* b2 = (const float*)d_in[20];

  float* ws = (float*)d_ws;
  float* gi = ws;               // 3,145,728 (overlaid with att)
  float* att = ws;              // 4,194,304
  float* val = ws + 4194304;    // 1,048,576
  float* ktab = ws + 5242880;   // 8,192
  float* w1p = ws + 5251072;    // 3,200
  float* b1p = ws + 5254272;    // 64
  float* out = (float*)d_out;

  prep_all_kernel<<<131, 256, 0, stream>>>(
      refq, Wk, bk, Wv, bv, W1, b1, z, Wih_f, bih_f, bhh_f, Wih_b, bih_b,
      bhh_b, ktab, w1p, b1p, gi);
  gru_kernel<<<32, 64, 0, stream>>>(gi, Whh_f, bhh_f, Whh_b, bhh_b, val);
  attn_core_kernel<<<1024, 256, 0, stream>>>(ts, ktab, val, Wq, bq, att);
  mlp_kernel<<<256, 256, 0, stream>>>(att, w1p, b1p, W2, b2, out);
}